// Round 9
// baseline (1571.817 us; speedup 1.0000x reference)
//
#include <hip/hip_runtime.h>
#include <hip/hip_bf16.h>

// ---------------------------------------------------------------------------
// PointNet++ critic forward. B=32, N=4096.
// R9: (1) fps1 1024 threads (4 waves/SIMD latency hiding), fps2 128.
// (2) bf16 hi/lo split via packed v_cvt_pk_bf16_f32 (__float22bfloat162_rn)
// in all MFMA kernels. (3) single fused weight-pack launch.
// ---------------------------------------------------------------------------

typedef __attribute__((ext_vector_type(8))) short short8;
typedef __attribute__((ext_vector_type(4))) float f32x4;
union SV8 { short8 v; ushort u[8]; unsigned w[4]; };

__device__ __forceinline__ ushort f2bf(float x) {
    unsigned u = __float_as_uint(x);
    unsigned r = (u + 0x7fffu + ((u >> 16) & 1u)) >> 16;   // RNE
    return (ushort)r;
}
__device__ __forceinline__ float bf2f(ushort h) {
    return __uint_as_float(((unsigned)h) << 16);
}

// packed hi/lo split: 8 floats -> bf16 hi + lo fragments (v_cvt_pk_bf16_f32)
__device__ __forceinline__ void split8(const float* xv, SV8& ah, SV8& al) {
    #pragma unroll
    for (int j = 0; j < 4; ++j) {
        const float2 f = make_float2(xv[2*j], xv[2*j+1]);
        __hip_bfloat162 h2 = __float22bfloat162_rn(f);
        unsigned hu; __builtin_memcpy(&hu, &h2, 4);
        ah.w[j] = hu;
        const float bx = __uint_as_float(hu << 16);
        const float by = __uint_as_float(hu & 0xffff0000u);
        const float2 l = make_float2(f.x - bx, f.y - by);
        __hip_bfloat162 l2 = __float22bfloat162_rn(l);
        unsigned lu; __builtin_memcpy(&lu, &l2, 4);
        al.w[j] = lu;
    }
}

// ======================= DPP wave64 max-reduce (u64) =======================
template<int CTRL>
__device__ __forceinline__ unsigned long long dpp_mov_u64(unsigned long long x) {
    const int lo = (int)(unsigned)(x & 0xffffffffull);
    const int hi = (int)(unsigned)(x >> 32);
    const int nlo = __builtin_amdgcn_update_dpp(lo, lo, CTRL, 0xf, 0xf, false);
    const int nhi = __builtin_amdgcn_update_dpp(hi, hi, CTRL, 0xf, 0xf, false);
    return ((unsigned long long)(unsigned)nhi << 32) | (unsigned)nlo;
}

__device__ __forceinline__ unsigned long long wave_max_u64(unsigned long long x) {
    unsigned long long y;
    y = dpp_mov_u64<0x111>(x); if (y > x) x = y;   // row_shr:1
    y = dpp_mov_u64<0x112>(x); if (y > x) x = y;   // row_shr:2
    y = dpp_mov_u64<0x114>(x); if (y > x) x = y;   // row_shr:4
    y = dpp_mov_u64<0x118>(x); if (y > x) x = y;   // row_shr:8
    y = dpp_mov_u64<0x142>(x); if (y > x) x = y;   // row_bcast:15
    y = dpp_mov_u64<0x143>(x); if (y > x) x = y;   // row_bcast:31
    return x;
}

// ============================ FPS ==========================================
template<int N, int S, int NT, bool CHW>
__global__ __launch_bounds__(NT)
void fps_kernel(const float* __restrict__ xyz, float* __restrict__ new_xyz) {
    constexpr int P  = N / NT;
    constexpr int NW = NT / 64;
    __shared__ __align__(16) float4 sxyz[N];
    __shared__ __align__(16) unsigned long long rv[2][NW > 1 ? NW : 2];
    const int b = blockIdx.x, t = threadIdx.x;
    float px[P], py[P], pz[P], dist[P];
    if (CHW) {
        const float* base = xyz + (size_t)b * 3 * N;
        #pragma unroll
        for (int p = 0; p < P; ++p) {
            const int i = p * NT + t;
            px[p] = base[i]; py[p] = base[N + i]; pz[p] = base[2 * N + i];
            sxyz[i] = make_float4(px[p], py[p], pz[p], 0.0f);
        }
    } else {
        const float* base = xyz + (size_t)b * N * 3;
        #pragma unroll
        for (int p = 0; p < P; ++p) {
            const int i = p * NT + t;
            px[p] = base[i*3]; py[p] = base[i*3+1]; pz[p] = base[i*3+2];
            sxyz[i] = make_float4(px[p], py[p], pz[p], 0.0f);
        }
    }
    #pragma unroll
    for (int p = 0; p < P; ++p) dist[p] = 1e10f;
    __syncthreads();
    int far = 0;
    float* out = new_xyz + (size_t)b * S * 3;
    for (int j = 0; j < S; ++j) {
        const float4 cen = sxyz[far];            // broadcast b128
        if (t == 0) { out[j*3+0] = cen.x; out[j*3+1] = cen.y; out[j*3+2] = cen.z; }
        float bv = -1.0f; int bi = 0;
        #pragma unroll
        for (int p = 0; p < P; ++p) {
            const int i = p * NT + t;
            const float dx = px[p] - cen.x, dy = py[p] - cen.y, dz = pz[p] - cen.z;
            // match reference rounding exactly: no FMA contraction
            const float d = __fadd_rn(__fadd_rn(__fmul_rn(dx, dx), __fmul_rn(dy, dy)), __fmul_rn(dz, dz));
            const float nd = fminf(dist[p], d);
            dist[p] = nd;
            if (nd > bv) { bv = nd; bi = i; }    // strict > keeps smallest i
        }
        unsigned long long pk =
            ((unsigned long long)__float_as_uint(bv) << 32) | (unsigned)(N - 1 - bi);
        pk = wave_max_u64(pk);
        if constexpr (NW > 1) {
            const int sl = j & 1;
            if ((t & 63) == 63) rv[sl][t >> 6] = pk;
            __syncthreads();
            unsigned long long best = rv[sl][0];
            #pragma unroll
            for (int w = 1; w < NW; ++w) { const unsigned long long v = rv[sl][w]; if (v > best) best = v; }
            far = N - 1 - (int)(best & 0xffffffffull);
        } else {
            far = N - 1 - __builtin_amdgcn_readlane((int)(pk & 0xffffffffull), 63);
        }
    }
}

// ============================ Ball query ===================================
template<int N, int NS, bool CHW, int NT>
__global__ __launch_bounds__(NT)
void bq_kernel(float r2, const float* __restrict__ xyz, const float* __restrict__ cen,
               int* __restrict__ gidx, int S) {
    constexpr int WPB = NT / 64;
    __shared__ __align__(16) float4 sp[N];
    const int t = threadIdx.x, lane = t & 63, w = t >> 6;
    const int cen0 = blockIdx.x * WPB;
    const int b = cen0 / S;                     // WPB divides S -> same batch
    if (CHW) {
        const float* base = xyz + (size_t)b * 3 * N;
        for (int i = t; i < N; i += NT)
            sp[i] = make_float4(base[i], base[N + i], base[2 * N + i], 0.0f);
    } else {
        const float* base = xyz + (size_t)b * N * 3;
        for (int i = t; i < N; i += NT)
            sp[i] = make_float4(base[i*3], base[i*3+1], base[i*3+2], 0.0f);
    }
    __syncthreads();
    const int wid = cen0 + w;
    const float cx = cen[(size_t)wid*3+0], cy = cen[(size_t)wid*3+1], cz = cen[(size_t)wid*3+2];
    int* out = gidx + (size_t)wid * NS;
    int cnt = 0, first = -1;
    for (int b0 = 0; b0 < N; b0 += 64) {
        const float4 p = sp[b0 + lane];
        const float dx = p.x - cx, dy = p.y - cy, dz = p.z - cz;
        const float d = __fadd_rn(__fadd_rn(__fmul_rn(dx, dx), __fmul_rn(dy, dy)), __fmul_rn(dz, dz));
        const bool in = (d <= r2);
        const unsigned long long m = __ballot(in);
        if (first < 0 && m != 0ull) first = b0 + __ffsll((unsigned long long)m) - 1;
        const int pos = cnt + (int)__popcll(m & ((1ull << lane) - 1ull));
        if (in && pos < NS) out[pos] = b0 + lane;
        cnt += (int)__popcll(m);
        if (cnt >= NS) break;
    }
    if (cnt < NS)
        for (int k = cnt + lane; k < NS; k += 64) out[k] = first;
}

// ==================== fused weight split + tile pack =======================
// layout: idx = ((ks*OTILES + ot)*64 + lane)*8 + j ; o = ot*16 + (lane&15),
// c = cofs + ks*32 + (lane>>4)*8 + j ; zero-pad c >= Ktot.
__device__ __forceinline__ void packg(const float* __restrict__ src,
                                      ushort* __restrict__ dh, ushort* __restrict__ dl,
                                      int Ktot, int otiles, int cofs, int idx) {
    const int j = idx & 7, lane = (idx >> 3) & 63;
    const int ot = (idx >> 9) % otiles;
    const int ks = idx / (512 * otiles);
    const int m = lane & 15, q = lane >> 4;
    const int o = ot * 16 + m, c = cofs + ks * 32 + q * 8 + j;
    const float v = (c < Ktot) ? src[(size_t)o * Ktot + c] : 0.0f;
    const ushort h = f2bf(v);
    dh[idx] = h;
    dl[idx] = f2bf(v - bf2f(h));
}

__global__ __launch_bounds__(256)
void prep_kernel(const float* s1w0, const float* s1b0, float4* Wc1,
                 const float* s1w1, ushort* M1W1h, ushort* M1W1l,
                 const float* s1w2, ushort* M1W2h, ushort* M1W2l,
                 const float* s3w0, ushort* S3W0h, ushort* S3W0l,
                 const float* s3w1, ushort* S3W1h, ushort* S3W1l,
                 const float* s3w2, ushort* S3W2h, ushort* S3W2l,
                 const float* s2w0, const float* s2b0, float4* Wc0,
                 ushort* W0h, ushort* W0l,
                 const float* s2w1, ushort* W1h, ushort* W1l,
                 const float* s2w2, ushort* W2h, ushort* W2l) {
    int i = blockIdx.x * 256 + threadIdx.x;
    if (i < 64)     { Wc1[i] = make_float4(s1w0[i*3], s1w0[i*3+1], s1w0[i*3+2], s1b0[i]); return; }  i -= 64;
    if (i < 4096)   { packg(s1w1, M1W1h, M1W1l,  64,  4, 0, i); return; }   i -= 4096;
    if (i < 8192)   { packg(s1w2, M1W2h, M1W2l,  64,  8, 0, i); return; }   i -= 8192;
    if (i < 73728)  { packg(s3w0, S3W0h, S3W0l, 259, 16, 0, i); return; }   i -= 73728;
    if (i < 131072) { packg(s3w1, S3W1h, S3W1l, 256, 32, 0, i); return; }   i -= 131072;
    if (i < 524288) { packg(s3w2, S3W2h, S3W2l, 512, 64, 0, i); return; }   i -= 524288;
    if (i < 16384)  { packg(s2w0, W0h, W0l, 131,  8, 3, i); return; }       i -= 16384;
    if (i < 16384)  { packg(s2w1, W1h, W1l, 128,  8, 0, i); return; }       i -= 16384;
    if (i < 32768)  { packg(s2w2, W2h, W2l, 128, 16, 0, i); return; }       i -= 32768;
    if (i < 128) {
        Wc0[i] = make_float4(s2w0[(size_t)i*131+0], s2w0[(size_t)i*131+1],
                             s2w0[(size_t)i*131+2], s2b0[i]);
    }
}

// ============================ MLP stage 1 (MFMA) ===========================
// grid (256, 32): 2 s (64 rows) per block, 4 waves; all LDS bands wave-private.
__global__ __launch_bounds__(256)
void mlp1_kernel(const float* __restrict__ xyz, const float* __restrict__ l1xyz,
                 const int* __restrict__ gidx, const float4* __restrict__ Wc1,
                 const ushort* __restrict__ W1h, const ushort* __restrict__ W1l,
                 const float* __restrict__ b1,
                 const ushort* __restrict__ W2h, const ushort* __restrict__ W2l,
                 const float* __restrict__ b2,
                 float* __restrict__ l1p) {
    __shared__ __align__(16) float bufA[64 * 68];   // h0, later max-partials
    __shared__ __align__(16) float bufB[64 * 68];   // g (first 256), later h1
    const int t = threadIdx.x, b = blockIdx.y, s0 = blockIdx.x * 2;
    {
        const int n = t >> 2, c = t & 3;
        const int s = s0 + (n >> 5);
        const int gi = gidx[((size_t)b * 512 + s) * 32 + (n & 31)];
        float v = 0.0f;
        if (c < 3) v = xyz[(size_t)b * 3 * 4096 + c * 4096 + gi] - l1xyz[((size_t)b * 512 + s) * 3 + c];
        bufB[n * 4 + c] = v;
    }
    __syncthreads();
    {   // layer0: 3 -> 64, exact fp32
        const int o = t & 63, ng = t >> 6;
        const float4 wc = Wc1[o];
        #pragma unroll
        for (int r = 0; r < 16; ++r) {
            const int n = ng * 16 + r;
            const float z = wc.w + wc.x * bufB[n*4] + wc.y * bufB[n*4+1] + wc.z * bufB[n*4+2];
            bufA[n * 68 + o] = fmaxf(z, 0.0f);
        }
    }
    const int lane = t & 63, wv = t >> 6;
    const int m = lane & 15, q = lane >> 4;
    const int rowA = wv * 16 + m;
    // layer1: 64 -> 64 (2 ksteps, 4 otiles)  [wave-private h0 band]
    f32x4 acc1[4];
    #pragma unroll
    for (int ot = 0; ot < 4; ++ot)
        #pragma unroll
        for (int r = 0; r < 4; ++r) acc1[ot][r] = 0.0f;
    #pragma unroll
    for (int ks = 0; ks < 2; ++ks) {
        float xv[8];
        *(float4*)&xv[0] = *(const float4*)&bufA[rowA * 68 + ks * 32 + q * 8];
        *(float4*)&xv[4] = *(const float4*)&bufA[rowA * 68 + ks * 32 + q * 8 + 4];
        SV8 ah, al; split8(xv, ah, al);
        #pragma unroll
        for (int ot = 0; ot < 4; ++ot) {
            SV8 bh, bl;
            bh.v = *(const short8*)(W1h + (size_t)((ks * 4 + ot) * 64 + lane) * 8);
            bl.v = *(const short8*)(W1l + (size_t)((ks * 4 + ot) * 64 + lane) * 8);
            acc1[ot] = __builtin_amdgcn_mfma_f32_16x16x32_bf16(ah.v, bh.v, acc1[ot], 0, 0, 0);
            acc1[ot] = __builtin_amdgcn_mfma_f32_16x16x32_bf16(al.v, bh.v, acc1[ot], 0, 0, 0);
            acc1[ot] = __builtin_amdgcn_mfma_f32_16x16x32_bf16(ah.v, bl.v, acc1[ot], 0, 0, 0);
        }
    }
    #pragma unroll
    for (int ot = 0; ot < 4; ++ot) {
        const float bb = b1[ot * 16 + m];
        #pragma unroll
        for (int r = 0; r < 4; ++r)
            bufB[(wv * 16 + q * 4 + r) * 68 + ot * 16 + m] = fmaxf(acc1[ot][r] + bb, 0.0f);
    }
    // layer2: 64 -> 128 (2 ksteps, 8 otiles) + per-wave max  [wave-private]
    f32x4 acc2[8];
    #pragma unroll
    for (int ot = 0; ot < 8; ++ot)
        #pragma unroll
        for (int r = 0; r < 4; ++r) acc2[ot][r] = 0.0f;
    #pragma unroll
    for (int ks = 0; ks < 2; ++ks) {
        float xv[8];
        *(float4*)&xv[0] = *(const float4*)&bufB[rowA * 68 + ks * 32 + q * 8];
        *(float4*)&xv[4] = *(const float4*)&bufB[rowA * 68 + ks * 32 + q * 8 + 4];
        SV8 ah, al; split8(xv, ah, al);
        #pragma unroll
        for (int ot = 0; ot < 8; ++ot) {
            SV8 bh, bl;
            bh.v = *(const short8*)(W2h + (size_t)((ks * 8 + ot) * 64 + lane) * 8);
            bl.v = *(const short8*)(W2l + (size_t)((ks * 8 + ot) * 64 + lane) * 8);
            acc2[ot] = __builtin_amdgcn_mfma_f32_16x16x32_bf16(ah.v, bh.v, acc2[ot], 0, 0, 0);
            acc2[ot] = __builtin_amdgcn_mfma_f32_16x16x32_bf16(al.v, bh.v, acc2[ot], 0, 0, 0);
            acc2[ot] = __builtin_amdgcn_mfma_f32_16x16x32_bf16(ah.v, bl.v, acc2[ot], 0, 0, 0);
        }
    }
    __syncthreads();
    #pragma unroll
    for (int ot = 0; ot < 8; ++ot) {
        const float bb = b2[ot * 16 + m];
        float mx = 0.0f;
        #pragma unroll
        for (int r = 0; r < 4; ++r) mx = fmaxf(mx, acc2[ot][r] + bb);
        bufA[(wv * 4 + q) * 128 + ot * 16 + m] = mx;
    }
    __syncthreads();
    {
        const int half = t >> 7, o = t & 127;
        float v = bufA[(half * 8) * 128 + o];
        #pragma unroll
        for (int rr = 1; rr < 8; ++rr) v = fmaxf(v, bufA[(half * 8 + rr) * 128 + o]);
        l1p[((size_t)b * 512 + s0 + half) * 128 + o] = v;
    }
}

// ============================ MLP stage 2 (MFMA) ===========================
__global__ __launch_bounds__(256)
void mlp2_kernel(const float* __restrict__ l1xyz, const float* __restrict__ l1p,
                 const float* __restrict__ l2xyz, const int* __restrict__ gidx,
                 const ushort* __restrict__ W0h, const ushort* __restrict__ W0l,
                 const float4* __restrict__ Wc0,
                 const ushort* __restrict__ W1h, const ushort* __restrict__ W1l,
                 const float* __restrict__ b1,
                 const ushort* __restrict__ W2h, const ushort* __restrict__ W2l,
                 const float* __restrict__ b2,
                 float* __restrict__ X3) {
    __shared__ __align__(16) float Abuf[64 * 132];   // x / h2
    __shared__ __align__(16) float Bbuf[64 * 132];   // h1 / max-partials
    __shared__ int sg[64];
    const int t = threadIdx.x, bs = blockIdx.x, b = bs >> 7;
    if (t < 64) sg[t] = gidx[(size_t)bs * 64 + t];
    if (t < 3)  X3[(size_t)bs * 288 + t] = l2xyz[(size_t)bs * 3 + t];     // raw coords
    if (t >= 64 && t < 93) X3[(size_t)bs * 288 + 259 + (t - 64)] = 0.0f;  // zero pad
    __syncthreads();
    for (int i = t; i < 64 * 32; i += 256) {
        const int n = i >> 5, cc = i & 31;
        *(float4*)&Abuf[n * 132 + cc * 4] =
            *(const float4*)&l1p[((size_t)b * 512 + sg[n]) * 128 + cc * 4];
    }
    if (t < 192) {
        const int n = t / 3, c = t % 3;
        Abuf[n * 132 + 128 + c] =
            l1xyz[((size_t)b * 512 + sg[n]) * 3 + c] - l2xyz[(size_t)bs * 3 + c];
    }
    __syncthreads();
    const int lane = t & 63, wv = t >> 6;
    const int m = lane & 15, q = lane >> 4;
    const int rowA = wv * 16 + m;

    // layer 0: feats (K=128) MFMA + coords/bias epilogue
    f32x4 acc0[8];
    #pragma unroll
    for (int ot = 0; ot < 8; ++ot)
        #pragma unroll
        for (int r = 0; r < 4; ++r) acc0[ot][r] = 0.0f;
    #pragma unroll
    for (int ks = 0; ks < 4; ++ks) {
        float xv[8];
        *(float4*)&xv[0] = *(const float4*)&Abuf[rowA * 132 + ks * 32 + q * 8];
        *(float4*)&xv[4] = *(const float4*)&Abuf[rowA * 132 + ks * 32 + q * 8 + 4];
        SV8 ah, al; split8(xv, ah, al);
        #pragma unroll
        for (int ot = 0; ot < 8; ++ot) {
            SV8 bh, bl;
            bh.v = *(const short8*)(W0h + (size_t)((ks * 8 + ot) * 64 + lane) * 8);
            bl.v = *(const short8*)(W0l + (size_t)((ks * 8 + ot) * 64 + lane) * 8);
            acc0[ot] = __builtin_amdgcn_mfma_f32_16x16x32_bf16(ah.v, bh.v, acc0[ot], 0, 0, 0);
            acc0[ot] = __builtin_amdgcn_mfma_f32_16x16x32_bf16(al.v, bh.v, acc0[ot], 0, 0, 0);
            acc0[ot] = __builtin_amdgcn_mfma_f32_16x16x32_bf16(ah.v, bl.v, acc0[ot], 0, 0, 0);
        }
    }
    float crd[4][3];
    #pragma unroll
    for (int r = 0; r < 4; ++r) {
        const int n = wv * 16 + q * 4 + r;
        crd[r][0] = Abuf[n * 132 + 128];
        crd[r][1] = Abuf[n * 132 + 129];
        crd[r][2] = Abuf[n * 132 + 130];
    }
    #pragma unroll
    for (int ot = 0; ot < 8; ++ot) {
        const float4 wc = Wc0[ot * 16 + m];
        #pragma unroll
        for (int r = 0; r < 4; ++r) {
            const float v = acc0[ot][r] + wc.w + wc.x * crd[r][0] + wc.y * crd[r][1] + wc.z * crd[r][2];
            Bbuf[(wv * 16 + q * 4 + r) * 132 + ot * 16 + m] = fmaxf(v, 0.0f);
        }
    }
    __syncthreads();

    // layer 1: 128 -> 128
    f32x4 acc1[8];
    #pragma unroll
    for (int ot = 0; ot < 8; ++ot)
        #pragma unroll
        for (int r = 0; r < 4; ++r) acc1[ot][r] = 0.0f;
    #pragma unroll
    for (int ks = 0; ks < 4; ++ks) {
        float xv[8];
        *(float4*)&xv[0] = *(const float4*)&Bbuf[rowA * 132 + ks * 32 + q * 8];
        *(float4*)&xv[4] = *(const float4*)&Bbuf[rowA * 132 + ks * 32 + q * 8 + 4];
        SV8 ah, al; split8(xv, ah, al);
        #pragma unroll
        for (int ot = 0; ot < 8; ++ot) {
            SV8 bh, bl;
            bh.v = *(const short8*)(W1h + (size_t)((ks * 8 + ot) * 64 + lane) * 8);
            bl.v = *(const short8*)(W1l + (size_t)((ks * 8 + ot) * 64 + lane) * 8);
            acc1[ot] = __builtin_amdgcn_mfma_f32_16x16x32_bf16(ah.v, bh.v, acc1[ot], 0, 0, 0);
            acc1[ot] = __builtin_amdgcn_mfma_f32_16x16x32_bf16(al.v, bh.v, acc1[ot], 0, 0, 0);
            acc1[ot] = __builtin_amdgcn_mfma_f32_16x16x32_bf16(ah.v, bl.v, acc1[ot], 0, 0, 0);
        }
    }
    __syncthreads();
    #pragma unroll
    for (int ot = 0; ot < 8; ++ot) {
        const float bb = b1[ot * 16 + m];
        #pragma unroll
        for (int r = 0; r < 4; ++r)
            Abuf[(wv * 16 + q * 4 + r) * 132 + ot * 16 + m] = fmaxf(acc1[ot][r] + bb, 0.0f);
    }
    __syncthreads();

    // layer 2: 128 -> 256, relu+max
    f32x4 acc2[16];
    #pragma unroll
    for (int ot = 0; ot < 16; ++ot)
        #pragma unroll
        for (int r = 0; r < 4; ++r) acc2[ot][r] = 0.0f;
    #pragma unroll
    for (int ks = 0; ks < 4; ++ks) {
        float xv[8];
        *(float4*)&xv[0] = *(const float4*)&Abuf[rowA * 132 + ks * 32 + q * 8];
        *(float4*)&xv[4] = *(const float4*)&Abuf[rowA * 132 + ks * 32 + q * 8 + 4];
        SV8 ah, al; split8(xv, ah, al);
        #pragma unroll
        for (int ot = 0; ot < 16; ++ot) {
            SV8 bh, bl;
            bh.v = *(const short8*)(W2h + (size_t)((ks * 16 + ot) * 64 + lane) * 8);
            bl.v = *(const short8*)(W2l + (size_t)((ks * 16 + ot) * 64 + lane) * 8);
            acc2[ot] = __builtin_amdgcn_mfma_f32_16x16x32_bf16(ah.v, bh.v, acc2[ot], 0, 0, 0);
            acc2[ot] = __builtin_amdgcn_mfma_f32_16x16x32_bf16(al.v, bh.v, acc2[ot], 0, 0, 0);
            acc2[ot] = __builtin_amdgcn_mfma_f32_16x16x32_bf16(ah.v, bl.v, acc2[ot], 0, 0, 0);
        }
    }
    __syncthreads();
    #pragma unroll
    for (int ot = 0; ot < 16; ++ot) {
        const float bb = b2[ot * 16 + m];
        float mx = 0.0f;
        #pragma unroll
        for (int r = 0; r < 4; ++r) mx = fmaxf(mx, acc2[ot][r] + bb);
        Bbuf[(wv * 4 + q) * 256 + ot * 16 + m] = mx;
    }
    __syncthreads();
    {
        float v = Bbuf[t];
        #pragma unroll
        for (int rr = 1; rr < 16; ++rr) v = fmaxf(v, Bbuf[rr * 256 + t]);
        X3[(size_t)bs * 288 + 3 + t] = v;
    }
}

// ===================== stage-3 GEMM via MFMA (no LDS A) ====================
template<int KSTEPS, bool MAXOUT>
__global__ __launch_bounds__(256)
void gemm_mfma_kernel(const float* __restrict__ A, int AS,
                      const ushort* __restrict__ Wh, const ushort* __restrict__ Wl,
                      const float* __restrict__ bias, float* __restrict__ C, int O) {
    __shared__ float part[16][64];
    const int t = threadIdx.x, lane = t & 63, wv = t >> 6;
    const int m = lane & 15, q = lane >> 4;
    const int rowA = blockIdx.x * 64 + wv * 16 + m;
    const int bo = blockIdx.y, OT = O >> 4;
    f32x4 acc[4];
    #pragma unroll
    for (int ot = 0; ot < 4; ++ot)
        #pragma unroll
        for (int r = 0; r < 4; ++r) acc[ot][r] = 0.0f;
    for (int ks = 0; ks < KSTEPS; ++ks) {
        float xv[8];
        *(float4*)&xv[0] = *(const float4*)&A[(size_t)rowA * AS + ks * 32 + q * 8];
        *(float4*)&xv[4] = *(const float4*)&A[(size_t)rowA * AS + ks * 32 + q * 8 + 4];
        SV8 ah, al; split8(xv, ah, al);
        #pragma unroll
        for (int ot = 0; ot < 4; ++ot) {
            const size_t wb = (size_t)((ks * OT + bo * 4 + ot) * 64 + lane) * 8;
            SV8 bh, bl;
            bh.v = *(const short8*)(Wh + wb);
            bl.v = *(const short8*)(Wl + wb);
            acc[ot] = __builtin_amdgcn_mfma_f32_16x16x32_bf16(ah.v, bh.v, acc[ot], 0, 0, 0);
            acc[ot] = __builtin_amdgcn_mfma_f32_16x16x32_bf16(al.v, bh.v, acc[ot], 0, 0, 0);
            acc[ot] = __builtin_amdgcn_mfma_f32_16x16x32_bf16(ah.v, bl.v, acc[ot], 0, 0, 0);
        }
    }
    if (!MAXOUT) {
        #pragma unroll
        for (int ot = 0; ot < 4; ++ot) {
            const int col = (bo * 4 + ot) * 16 + m;
            const float bb = bias[col];
            #pragma unroll
            for (int r = 0; r < 4; ++r) {
                const int row = blockIdx.x * 64 + wv * 16 + q * 4 + r;
                C[(size_t)row * O + col] = fmaxf(acc[ot][r] + bb, 0.0f);
            }
        }
    } else {
        #pragma unroll
        for (int ot = 0; ot < 4; ++ot) {
            const int col = (bo * 4 + ot) * 16 + m;
            const float bb = bias[col];
            float mx = 0.0f;
            #pragma unroll
            for (int r = 0; r < 4; ++r) mx = fmaxf(mx, acc[ot][r] + bb);
            part[wv * 4 + q][ot * 16 + m] = mx;
        }
        __syncthreads();
        if (t < 64) {
            float v = part[0][t];
            #pragma unroll
            for (int rr = 1; rr < 16; ++rr) v = fmaxf(v, part[rr][t]);
            C[(size_t)blockIdx.x * O + bo * 64 + t] = v;
        }
    }
}

// ============================ Generic fp32 GEMM (FC head) ==================
template<bool RELU>
__global__ __launch_bounds__(256)
void gemm_kernel(const float* __restrict__ A, const float* __restrict__ W,
                 const float* __restrict__ bias, float* __restrict__ C,
                 int M, int K, int O) {
    __shared__ __align__(16) float At[32*68];
    __shared__ __align__(16) float Wt[32*68];
    const int t = threadIdx.x;
    const int mtile = blockIdx.x * 64, otile = blockIdx.y * 64;
    const int tx = t & 15, ty = t >> 4;
    float acc[4][4];
    #pragma unroll
    for (int i = 0; i < 4; ++i)
        #pragma unroll
        for (int j = 0; j < 4; ++j) acc[i][j] = 0.0f;
    const int kk = t & 31, r0 = t >> 5;
    for (int k0 = 0; k0 < K; k0 += 32) {
        #pragma unroll
        for (int rr = 0; rr < 8; ++rr) {
            const int row = r0 + rr * 8;
            const int m = mtile + row, o = otile + row, k = k0 + kk;
            At[kk*68 + row] = (m < M && k < K) ? A[(size_t)m*K + k] : 0.0f;
            Wt[kk*68 + row] = (o < O && k < K) ? W[(size_t)o*K + k] : 0.0f;
        }
        __syncthreads();
        #pragma unroll
        for (int k2 = 0; k2 < 32; ++k2) {
            const float4 av = *(const float4*)&At[k2*68 + tx*4];
            const float4 wv = *(const float4*)&Wt[k2*68 + ty*4];
            const float a[4] = {av.x, av.y, av.z, av.w};
            const float w[4] = {wv.x, wv.y, wv.z, wv.w};
            #pragma unroll
            for (int i = 0; i < 4; ++i)
                #pragma unroll
                for (int j = 0; j < 4; ++j) acc[i][j] += a[i] * w[j];
        }
        __syncthreads();
    }
    #pragma unroll
    for (int i = 0; i < 4; ++i) {
        const int m = mtile + tx*4 + i;
        if (m >= M) continue;
        #pragma unroll
        for (int j = 0; j < 4; ++j) {
            const int o = otile + ty*4 + j;
            if (o >= O) continue;
            float v = acc[i][j] + bias[o];
            if (RELU) v = fmaxf(v, 0.0f);
            C[(size_t)m*O + o] = v;
        }
    }
}

// ============================ final max (P3 -> feat) =======================
__global__ __launch_bounds__(256)
void maxfin_kernel(const float* __restrict__ P3, float* __restrict__ feat) {
    const int idx = blockIdx.x * 256 + threadIdx.x;  // 32*1024
    const int b = idx >> 10, o = idx & 1023;
    feat[idx] = fmaxf(P3[(size_t)(2*b) * 1024 + o], P3[(size_t)(2*b+1) * 1024 + o]);
}

// ============================ launch =======================================
extern "C" void kernel_launch(void* const* d_in, const int* in_sizes, int n_in,
                              void* d_out, int out_size, void* d_ws, size_t ws_size,
                              hipStream_t stream) {
    const float* xyz  = (const float*)d_in[0];
    const float* s1w0 = (const float*)d_in[1];  const float* s1b0 = (const float*)d_in[2];
    const float* s1w1 = (const float*)d_in[3];  const float* s1b1 = (const float*)d_in[4];
    const float* s1w2 = (const float*)d_in[5];  const float* s1b2 = (const float*)d_in[6];
    const float* s2w0 = (const float*)d_in[7];  const float* s2b0 = (const float*)d_in[8];
    const float* s2w1 = (const float*)d_in[9];  const float* s2b1 = (const float*)d_in[10];
    const float* s2w2 = (const float*)d_in[11]; const float* s2b2 = (const float*)d_in[12];
    const float* s3w0 = (const float*)d_in[13]; const float* s3b0 = (const float*)d_in[14];
    const float* s3w1 = (const float*)d_in[15]; const float* s3b1 = (const float*)d_in[16];
    const float* s3w2 = (const float*)d_in[17]; const float* s3b2 = (const float*)d_in[18];
    const float* f1w  = (const float*)d_in[19]; const float* f1b  = (const float*)d_in[20];
    const float* f2w  = (const float*)d_in[21]; const float* f2b  = (const float*)d_in[22];
    const float* f3w  = (const float*)d_in[23]; const float* f3b  = (const float*)d_in[24];

    char* ws = (char*)d_ws;
    float* l1_xyz = (float*)(ws + 0);              // 32*512*3
    int*   gidx1  = (int*)  (ws + 196608);         // 32*512*32
    float* l1p    = (float*)(ws + 2293760);        // 32*512*128
    float* l2_xyz = (float*)(ws + 10682368);       // 32*128*3
    int*   gidx2  = (int*)  (ws + 10731520);       // 32*128*64
    float* X3p    = (float*)(ws + 11780096);       // 4096*288 (zero-padded)
    const size_t PK = 16498688;                    // pack region
    float4* Wc1   = (float4*)(ws + PK + 0);
    ushort* M1W1h = (ushort*)(ws + PK + 1024);
    ushort* M1W1l = (ushort*)(ws + PK + 9216);
    ushort* M1W2h = (ushort*)(ws + PK + 17408);
    ushort* M1W2l = (ushort*)(ws + PK + 33792);
    ushort* W0h   = (ushort*)(ws + PK + 50176);
    ushort* W0l   = (ushort*)(ws + PK + 82944);
    ushort* W1h   = (ushort*)(ws + PK + 115712);
    ushort* W1l   = (ushort*)(ws + PK + 148480);
    ushort* W2h   = (ushort*)(ws + PK + 181248);
    ushort* W2l   = (ushort*)(ws + PK + 246784);
    float4* Wc0   = (float4*)(ws + PK + 312320);
    ushort* S3W0h = (ushort*)(ws + PK + 314368);
    ushort* S3W0l = (ushort*)(ws + PK + 461824);
    ushort* S3W1h = (ushort*)(ws + PK + 609280);
    ushort* S3W1l = (ushort*)(ws + PK + 871424);
    ushort* S3W2h = (ushort*)(ws + PK + 1133568);
    ushort* S3W2l = (ushort*)(ws + PK + 2182144);
    float* Y1   = (float*)(ws + 19729408);         // 4096*256
    float* Y2   = (float*)(ws + 23923712);         // 4096*512
    float* P3   = (float*)(ws + 32312320);         // 64*1024 partial maxima
    float* feat = (float*)(ws + 32574464);         // 32*1024
    float* fb1  = (float*)(ws + 32705536);         // 32*512
    float* fb2  = (float*)(ws + 32771072);         // 32*256

    // fused weight pack: 741440 + 65792 = 807232 items -> 3154 blocks
    prep_kernel<<<3154, 256, 0, stream>>>(s1w0, s1b0, Wc1,
        s1w1, M1W1h, M1W1l, s1w2, M1W2h, M1W2l,
        s3w0, S3W0h, S3W0l, s3w1, S3W1h, S3W1l, s3w2, S3W2h, S3W2l,
        s2w0, s2b0, Wc0, W0h, W0l, s2w1, W1h, W1l, s2w2, W2h, W2l);

    // Stage 1
    fps_kernel<4096, 512, 1024, true><<<32, 1024, 0, stream>>>(xyz, l1_xyz);
    bq_kernel<4096, 32, true, 1024><<<1024, 1024, 0, stream>>>(
        (float)(0.2 * 0.2), xyz, l1_xyz, gidx1, 512);
    {
        dim3 g(256, 32);
        mlp1_kernel<<<g, 256, 0, stream>>>(xyz, l1_xyz, gidx1,
            Wc1, M1W1h, M1W1l, s1b1, M1W2h, M1W2l, s1b2, l1p);
    }

    // Stage 2
    fps_kernel<512, 128, 128, false><<<32, 128, 0, stream>>>(l1_xyz, l2_xyz);
    bq_kernel<512, 64, false, 1024><<<256, 1024, 0, stream>>>(
        (float)(0.4 * 0.4), l1_xyz, l2_xyz, gidx2, 128);
    mlp2_kernel<<<4096, 256, 0, stream>>>(l1_xyz, l1p, l2_xyz, gidx2,
        W0h, W0l, Wc0, W1h, W1l, s2b1, W2h, W2l, s2b2, X3p);

    // Stage 3 (MFMA GEMMs; gemm3 fuses the 128-row max into P3)
    {
        dim3 g1(64, 4);
        gemm_mfma_kernel<9,  false><<<g1, 256, 0, stream>>>(X3p, 288, S3W0h, S3W0l, s3b0, Y1, 256);
        dim3 g2(64, 8);
        gemm_mfma_kernel<8,  false><<<g2, 256, 0, stream>>>(Y1, 256, S3W1h, S3W1l, s3b1, Y2, 512);
        dim3 g3(64, 16);
        gemm_mfma_kernel<16, true ><<<g3, 256, 0, stream>>>(Y2, 512, S3W2h, S3W2l, s3b2, P3, 1024);
    }
    maxfin_kernel<<<128, 256, 0, stream>>>(P3, feat);

    // FC head (fp32)
    {
        dim3 g1(1, 8); gemm_kernel<true><<<g1, 256, 0, stream>>>(feat, f1w, f1b, fb1, 32, 1024, 512);
        dim3 g2(1, 4); gemm_kernel<true><<<g2, 256, 0, stream>>>(fb1, f2w, f2b, fb2, 32, 512, 256);
        dim3 g3(1, 1); gemm_kernel<false><<<g3, 256, 0, stream>>>(fb2, f3w, f3b, (float*)d_out, 32, 256, 6);
    }
    (void)in_sizes; (void)n_in; (void)out_size; (void)ws_size;
}

// Round 10
// 1087.799 us; speedup vs baseline: 1.4450x; 1.4450x over previous
//
#include <hip/hip_runtime.h>
#include <hip/hip_bf16.h>

// ---------------------------------------------------------------------------
// PointNet++ critic forward. B=32, N=4096.
// R10: revert R9 regressions (fps NT=256, scalar f2bf). FPS inner argmax via
// packed-u64 4-level tree (precomputed index constants). Weight pack merged
// into the fps1 launch (idle-CU hiding); fps2 merged into the mlp1 launch.
// ---------------------------------------------------------------------------

typedef __attribute__((ext_vector_type(8))) short short8;
typedef __attribute__((ext_vector_type(4))) float f32x4;
union SV8 { short8 v; ushort u[8]; };

__device__ __forceinline__ ushort f2bf(float x) {
    unsigned u = __float_as_uint(x);
    unsigned r = (u + 0x7fffu + ((u >> 16) & 1u)) >> 16;   // RNE
    return (ushort)r;
}
__device__ __forceinline__ float bf2f(ushort h) {
    return __uint_as_float(((unsigned)h) << 16);
}

// ======================= DPP wave64 max-reduce (u64) =======================
template<int CTRL>
__device__ __forceinline__ unsigned long long dpp_mov_u64(unsigned long long x) {
    const int lo = (int)(unsigned)(x & 0xffffffffull);
    const int hi = (int)(unsigned)(x >> 32);
    const int nlo = __builtin_amdgcn_update_dpp(lo, lo, CTRL, 0xf, 0xf, false);
    const int nhi = __builtin_amdgcn_update_dpp(hi, hi, CTRL, 0xf, 0xf, false);
    return ((unsigned long long)(unsigned)nhi << 32) | (unsigned)nlo;
}

__device__ __forceinline__ unsigned long long wave_max_u64(unsigned long long x) {
    unsigned long long y;
    y = dpp_mov_u64<0x111>(x); if (y > x) x = y;   // row_shr:1
    y = dpp_mov_u64<0x112>(x); if (y > x) x = y;   // row_shr:2
    y = dpp_mov_u64<0x114>(x); if (y > x) x = y;   // row_shr:4
    y = dpp_mov_u64<0x118>(x); if (y > x) x = y;   // row_shr:8
    y = dpp_mov_u64<0x142>(x); if (y > x) x = y;   // row_bcast:15
    y = dpp_mov_u64<0x143>(x); if (y > x) x = y;   // row_bcast:31
    return x;
}

// ============================ FPS body =====================================
// smem layout: float4 sxyz[N]; u64 rv[2*NW].
template<int N, int S, int NT, bool CHW>
__device__ __forceinline__ void fps_body(const float* __restrict__ xyz,
                                         float* __restrict__ new_xyz,
                                         int b, int t, char* smem) {
    constexpr int P  = N / NT;
    constexpr int NW = NT / 64;
    float4* sxyz = (float4*)smem;
    unsigned long long* rv = (unsigned long long*)(smem + (size_t)N * 16);
    float px[P], py[P], pz[P], dist[P];
    unsigned idc[P];
    if (CHW) {
        const float* base = xyz + (size_t)b * 3 * N;
        #pragma unroll
        for (int p = 0; p < P; ++p) {
            const int i = p * NT + t;
            px[p] = base[i]; py[p] = base[N + i]; pz[p] = base[2 * N + i];
            sxyz[i] = make_float4(px[p], py[p], pz[p], 0.0f);
        }
    } else {
        const float* base = xyz + (size_t)b * N * 3;
        #pragma unroll
        for (int p = 0; p < P; ++p) {
            const int i = p * NT + t;
            px[p] = base[i*3]; py[p] = base[i*3+1]; pz[p] = base[i*3+2];
            sxyz[i] = make_float4(px[p], py[p], pz[p], 0.0f);
        }
    }
    #pragma unroll
    for (int p = 0; p < P; ++p) { dist[p] = 1e10f; idc[p] = (unsigned)(N - 1 - (p * NT + t)); }
    __syncthreads();
    int far = 0;
    float* out = new_xyz + (size_t)b * S * 3;
    for (int j = 0; j < S; ++j) {
        const float4 cen = sxyz[far];            // broadcast b128
        if (t == 0) { out[j*3+0] = cen.x; out[j*3+1] = cen.y; out[j*3+2] = cen.z; }
        unsigned long long pk[P];
        #pragma unroll
        for (int p = 0; p < P; ++p) {
            const float dx = px[p] - cen.x, dy = py[p] - cen.y, dz = pz[p] - cen.z;
            // match reference rounding exactly: no FMA contraction
            const float d = __fadd_rn(__fadd_rn(__fmul_rn(dx, dx), __fmul_rn(dy, dy)), __fmul_rn(dz, dz));
            const float nd = fminf(dist[p], d);
            dist[p] = nd;
            pk[p] = ((unsigned long long)__float_as_uint(nd) << 32) | idc[p];
        }
        #pragma unroll
        for (int s = P / 2; s > 0; s >>= 1)
            #pragma unroll
            for (int k = 0; k < s; ++k)
                if (pk[k + s] > pk[k]) pk[k] = pk[k + s];
        unsigned long long best = wave_max_u64(pk[0]);
        if constexpr (NW > 1) {
            const int sl = (j & 1) * NW;
            if ((t & 63) == 63) rv[sl + (t >> 6)] = best;
            __syncthreads();
            unsigned long long bb = rv[sl];
            #pragma unroll
            for (int w = 1; w < NW; ++w) { const unsigned long long v = rv[sl + w]; if (v > bb) bb = v; }
            far = N - 1 - (int)(bb & 0xffffffffull);
        } else {
            far = N - 1 - __builtin_amdgcn_readlane((int)(best & 0xffffffffull), 63);
        }
    }
}

// ==================== weight split + tile pack bodies ======================
__device__ __forceinline__ void packg(const float* __restrict__ src,
                                      ushort* __restrict__ dh, ushort* __restrict__ dl,
                                      int Ktot, int otiles, int cofs, int idx) {
    const int j = idx & 7, lane = (idx >> 3) & 63;
    const int ot = (idx >> 9) % otiles;
    const int ks = idx / (512 * otiles);
    const int m = lane & 15, q = lane >> 4;
    const int o = ot * 16 + m, c = cofs + ks * 32 + q * 8 + j;
    const float v = (c < Ktot) ? src[(size_t)o * Ktot + c] : 0.0f;
    const ushort h = f2bf(v);
    dh[idx] = h;
    dl[idx] = f2bf(v - bf2f(h));
}

// ================= fps1 + weight pack, merged launch =======================
// blocks 0..31: FPS batch b. blocks 32..: pack work.
__global__ __launch_bounds__(256)
void fps1_prep_kernel(const float* __restrict__ xyz, float* __restrict__ l1xyz,
                 const float* s1w0, const float* s1b0, float4* Wc1,
                 const float* s1w1, ushort* M1W1h, ushort* M1W1l,
                 const float* s1w2, ushort* M1W2h, ushort* M1W2l,
                 const float* s3w0, ushort* S3W0h, ushort* S3W0l,
                 const float* s3w1, ushort* S3W1h, ushort* S3W1l,
                 const float* s3w2, ushort* S3W2h, ushort* S3W2l,
                 const float* s2w0, const float* s2b0, float4* Wc0,
                 ushort* W0h, ushort* W0l,
                 const float* s2w1, ushort* W1h, ushort* W1l,
                 const float* s2w2, ushort* W2h, ushort* W2l) {
    __shared__ __align__(16) char smem[4096 * 16 + 64];
    if (blockIdx.x < 32) {
        fps_body<4096, 512, 256, true>(xyz, l1xyz, blockIdx.x, threadIdx.x, smem);
        return;
    }
    int i = (blockIdx.x - 32) * 256 + threadIdx.x;
    if (i < 64)     { Wc1[i] = make_float4(s1w0[i*3], s1w0[i*3+1], s1w0[i*3+2], s1b0[i]); return; }  i -= 64;
    if (i < 4096)   { packg(s1w1, M1W1h, M1W1l,  64,  4, 0, i); return; }   i -= 4096;
    if (i < 8192)   { packg(s1w2, M1W2h, M1W2l,  64,  8, 0, i); return; }   i -= 8192;
    if (i < 73728)  { packg(s3w0, S3W0h, S3W0l, 259, 16, 0, i); return; }   i -= 73728;
    if (i < 131072) { packg(s3w1, S3W1h, S3W1l, 256, 32, 0, i); return; }   i -= 131072;
    if (i < 524288) { packg(s3w2, S3W2h, S3W2l, 512, 64, 0, i); return; }   i -= 524288;
    if (i < 16384)  { packg(s2w0, W0h, W0l, 131,  8, 3, i); return; }       i -= 16384;
    if (i < 16384)  { packg(s2w1, W1h, W1l, 128,  8, 0, i); return; }       i -= 16384;
    if (i < 32768)  { packg(s2w2, W2h, W2l, 128, 16, 0, i); return; }       i -= 32768;
    if (i < 128) {
        Wc0[i] = make_float4(s2w0[(size_t)i*131+0], s2w0[(size_t)i*131+1],
                             s2w0[(size_t)i*131+2], s2b0[i]);
    }
}

// ============================ Ball query ===================================
template<int N, int NS, bool CHW, int NT>
__global__ __launch_bounds__(NT)
void bq_kernel(float r2, const float* __restrict__ xyz, const float* __restrict__ cen,
               int* __restrict__ gidx, int S) {
    constexpr int WPB = NT / 64;
    __shared__ __align__(16) float4 sp[N];
    const int t = threadIdx.x, lane = t & 63, w = t >> 6;
    const int cen0 = blockIdx.x * WPB;
    const int b = cen0 / S;                     // WPB divides S -> same batch
    if (CHW) {
        const float* base = xyz + (size_t)b * 3 * N;
        for (int i = t; i < N; i += NT)
            sp[i] = make_float4(base[i], base[N + i], base[2 * N + i], 0.0f);
    } else {
        const float* base = xyz + (size_t)b * N * 3;
        for (int i = t; i < N; i += NT)
            sp[i] = make_float4(base[i*3], base[i*3+1], base[i*3+2], 0.0f);
    }
    __syncthreads();
    const int wid = cen0 + w;
    const float cx = cen[(size_t)wid*3+0], cy = cen[(size_t)wid*3+1], cz = cen[(size_t)wid*3+2];
    int* out = gidx + (size_t)wid * NS;
    int cnt = 0, first = -1;
    for (int b0 = 0; b0 < N; b0 += 64) {
        const float4 p = sp[b0 + lane];
        const float dx = p.x - cx, dy = p.y - cy, dz = p.z - cz;
        const float d = __fadd_rn(__fadd_rn(__fmul_rn(dx, dx), __fmul_rn(dy, dy)), __fmul_rn(dz, dz));
        const bool in = (d <= r2);
        const unsigned long long m = __ballot(in);
        if (first < 0 && m != 0ull) first = b0 + __ffsll((unsigned long long)m) - 1;
        const int pos = cnt + (int)__popcll(m & ((1ull << lane) - 1ull));
        if (in && pos < NS) out[pos] = b0 + lane;
        cnt += (int)__popcll(m);
        if (cnt >= NS) break;
    }
    if (cnt < NS)
        for (int k = cnt + lane; k < NS; k += 64) out[k] = first;
}

// ==================== MLP stage 1 (MFMA) + fps2 merged =====================
// grid (257, 32): x<256 -> mlp1 (2 s-tiles); x==256 -> fps2 for batch y.
__global__ __launch_bounds__(256)
void mlp1_kernel(const float* __restrict__ xyz, const float* __restrict__ l1xyz,
                 float* __restrict__ l2xyz,
                 const int* __restrict__ gidx, const float4* __restrict__ Wc1,
                 const ushort* __restrict__ W1h, const ushort* __restrict__ W1l,
                 const float* __restrict__ b1,
                 const ushort* __restrict__ W2h, const ushort* __restrict__ W2l,
                 const float* __restrict__ b2,
                 float* __restrict__ l1p) {
    __shared__ __align__(16) char smem[64 * 68 * 4 * 2];   // 34816 B
    float* bufA = (float*)smem;                  // h0, later max-partials
    float* bufB = (float*)(smem + 64 * 68 * 4);  // g, later h1
    const int t = threadIdx.x, b = blockIdx.y;
    if (blockIdx.x == 256) {   // fps2 (needs only l1xyz; 8256 B of smem)
        fps_body<512, 128, 256, false>(l1xyz, l2xyz, b, t, smem);
        return;
    }
    const int s0 = blockIdx.x * 2;
    {
        const int n = t >> 2, c = t & 3;
        const int s = s0 + (n >> 5);
        const int gi = gidx[((size_t)b * 512 + s) * 32 + (n & 31)];
        float v = 0.0f;
        if (c < 3) v = xyz[(size_t)b * 3 * 4096 + c * 4096 + gi] - l1xyz[((size_t)b * 512 + s) * 3 + c];
        bufB[n * 4 + c] = v;
    }
    __syncthreads();
    {   // layer0: 3 -> 64, exact fp32
        const int o = t & 63, ng = t >> 6;
        const float4 wc = Wc1[o];
        #pragma unroll
        for (int r = 0; r < 16; ++r) {
            const int n = ng * 16 + r;
            const float z = wc.w + wc.x * bufB[n*4] + wc.y * bufB[n*4+1] + wc.z * bufB[n*4+2];
            bufA[n * 68 + o] = fmaxf(z, 0.0f);
        }
    }
    const int lane = t & 63, wv = t >> 6;
    const int m = lane & 15, q = lane >> 4;
    const int rowA = wv * 16 + m;
    // layer1: 64 -> 64 (2 ksteps, 4 otiles)  [wave-private h0 band]
    f32x4 acc1[4];
    #pragma unroll
    for (int ot = 0; ot < 4; ++ot)
        #pragma unroll
        for (int r = 0; r < 4; ++r) acc1[ot][r] = 0.0f;
    #pragma unroll
    for (int ks = 0; ks < 2; ++ks) {
        float xv[8];
        *(float4*)&xv[0] = *(const float4*)&bufA[rowA * 68 + ks * 32 + q * 8];
        *(float4*)&xv[4] = *(const float4*)&bufA[rowA * 68 + ks * 32 + q * 8 + 4];
        SV8 ah, al;
        #pragma unroll
        for (int j = 0; j < 8; ++j) { ah.u[j] = f2bf(xv[j]); al.u[j] = f2bf(xv[j] - bf2f(ah.u[j])); }
        #pragma unroll
        for (int ot = 0; ot < 4; ++ot) {
            SV8 bh, bl;
            bh.v = *(const short8*)(W1h + (size_t)((ks * 4 + ot) * 64 + lane) * 8);
            bl.v = *(const short8*)(W1l + (size_t)((ks * 4 + ot) * 64 + lane) * 8);
            acc1[ot] = __builtin_amdgcn_mfma_f32_16x16x32_bf16(ah.v, bh.v, acc1[ot], 0, 0, 0);
            acc1[ot] = __builtin_amdgcn_mfma_f32_16x16x32_bf16(al.v, bh.v, acc1[ot], 0, 0, 0);
            acc1[ot] = __builtin_amdgcn_mfma_f32_16x16x32_bf16(ah.v, bl.v, acc1[ot], 0, 0, 0);
        }
    }
    #pragma unroll
    for (int ot = 0; ot < 4; ++ot) {
        const float bb = b1[ot * 16 + m];
        #pragma unroll
        for (int r = 0; r < 4; ++r)
            bufB[(wv * 16 + q * 4 + r) * 68 + ot * 16 + m] = fmaxf(acc1[ot][r] + bb, 0.0f);
    }
    // layer2: 64 -> 128 (2 ksteps, 8 otiles) + per-wave max  [wave-private]
    f32x4 acc2[8];
    #pragma unroll
    for (int ot = 0; ot < 8; ++ot)
        #pragma unroll
        for (int r = 0; r < 4; ++r) acc2[ot][r] = 0.0f;
    #pragma unroll
    for (int ks = 0; ks < 2; ++ks) {
        float xv[8];
        *(float4*)&xv[0] = *(const float4*)&bufB[rowA * 68 + ks * 32 + q * 8];
        *(float4*)&xv[4] = *(const float4*)&bufB[rowA * 68 + ks * 32 + q * 8 + 4];
        SV8 ah, al;
        #pragma unroll
        for (int j = 0; j < 8; ++j) { ah.u[j] = f2bf(xv[j]); al.u[j] = f2bf(xv[j] - bf2f(ah.u[j])); }
        #pragma unroll
        for (int ot = 0; ot < 8; ++ot) {
            SV8 bh, bl;
            bh.v = *(const short8*)(W2h + (size_t)((ks * 8 + ot) * 64 + lane) * 8);
            bl.v = *(const short8*)(W2l + (size_t)((ks * 8 + ot) * 64 + lane) * 8);
            acc2[ot] = __builtin_amdgcn_mfma_f32_16x16x32_bf16(ah.v, bh.v, acc2[ot], 0, 0, 0);
            acc2[ot] = __builtin_amdgcn_mfma_f32_16x16x32_bf16(al.v, bh.v, acc2[ot], 0, 0, 0);
            acc2[ot] = __builtin_amdgcn_mfma_f32_16x16x32_bf16(ah.v, bl.v, acc2[ot], 0, 0, 0);
        }
    }
    __syncthreads();
    #pragma unroll
    for (int ot = 0; ot < 8; ++ot) {
        const float bb = b2[ot * 16 + m];
        float mx = 0.0f;
        #pragma unroll
        for (int r = 0; r < 4; ++r) mx = fmaxf(mx, acc2[ot][r] + bb);
        bufA[(wv * 4 + q) * 128 + ot * 16 + m] = mx;
    }
    __syncthreads();
    {
        const int half = t >> 7, o = t & 127;
        float v = bufA[(half * 8) * 128 + o];
        #pragma unroll
        for (int rr = 1; rr < 8; ++rr) v = fmaxf(v, bufA[(half * 8 + rr) * 128 + o]);
        l1p[((size_t)b * 512 + s0 + half) * 128 + o] = v;
    }
}

// ============================ MLP stage 2 (MFMA) ===========================
__global__ __launch_bounds__(256)
void mlp2_kernel(const float* __restrict__ l1xyz, const float* __restrict__ l1p,
                 const float* __restrict__ l2xyz, const int* __restrict__ gidx,
                 const ushort* __restrict__ W0h, const ushort* __restrict__ W0l,
                 const float4* __restrict__ Wc0,
                 const ushort* __restrict__ W1h, const ushort* __restrict__ W1l,
                 const float* __restrict__ b1,
                 const ushort* __restrict__ W2h, const ushort* __restrict__ W2l,
                 const float* __restrict__ b2,
                 float* __restrict__ X3) {
    __shared__ __align__(16) float Abuf[64 * 132];   // x / h2
    __shared__ __align__(16) float Bbuf[64 * 132];   // h1 / max-partials
    __shared__ int sg[64];
    const int t = threadIdx.x, bs = blockIdx.x, b = bs >> 7;
    if (t < 64) sg[t] = gidx[(size_t)bs * 64 + t];
    if (t < 3)  X3[(size_t)bs * 288 + t] = l2xyz[(size_t)bs * 3 + t];     // raw coords
    if (t >= 64 && t < 93) X3[(size_t)bs * 288 + 259 + (t - 64)] = 0.0f;  // zero pad
    __syncthreads();
    for (int i = t; i < 64 * 32; i += 256) {
        const int n = i >> 5, cc = i & 31;
        *(float4*)&Abuf[n * 132 + cc * 4] =
            *(const float4*)&l1p[((size_t)b * 512 + sg[n]) * 128 + cc * 4];
    }
    if (t < 192) {
        const int n = t / 3, c = t % 3;
        Abuf[n * 132 + 128 + c] =
            l1xyz[((size_t)b * 512 + sg[n]) * 3 + c] - l2xyz[(size_t)bs * 3 + c];
    }
    __syncthreads();
    const int lane = t & 63, wv = t >> 6;
    const int m = lane & 15, q = lane >> 4;
    const int rowA = wv * 16 + m;

    // layer 0: feats (K=128) MFMA + coords/bias epilogue
    f32x4 acc0[8];
    #pragma unroll
    for (int ot = 0; ot < 8; ++ot)
        #pragma unroll
        for (int r = 0; r < 4; ++r) acc0[ot][r] = 0.0f;
    #pragma unroll
    for (int ks = 0; ks < 4; ++ks) {
        float xv[8];
        *(float4*)&xv[0] = *(const float4*)&Abuf[rowA * 132 + ks * 32 + q * 8];
        *(float4*)&xv[4] = *(const float4*)&Abuf[rowA * 132 + ks * 32 + q * 8 + 4];
        SV8 ah, al;
        #pragma unroll
        for (int j = 0; j < 8; ++j) { ah.u[j] = f2bf(xv[j]); al.u[j] = f2bf(xv[j] - bf2f(ah.u[j])); }
        #pragma unroll
        for (int ot = 0; ot < 8; ++ot) {
            SV8 bh, bl;
            bh.v = *(const short8*)(W0h + (size_t)((ks * 8 + ot) * 64 + lane) * 8);
            bl.v = *(const short8*)(W0l + (size_t)((ks * 8 + ot) * 64 + lane) * 8);
            acc0[ot] = __builtin_amdgcn_mfma_f32_16x16x32_bf16(ah.v, bh.v, acc0[ot], 0, 0, 0);
            acc0[ot] = __builtin_amdgcn_mfma_f32_16x16x32_bf16(al.v, bh.v, acc0[ot], 0, 0, 0);
            acc0[ot] = __builtin_amdgcn_mfma_f32_16x16x32_bf16(ah.v, bl.v, acc0[ot], 0, 0, 0);
        }
    }
    float crd[4][3];
    #pragma unroll
    for (int r = 0; r < 4; ++r) {
        const int n = wv * 16 + q * 4 + r;
        crd[r][0] = Abuf[n * 132 + 128];
        crd[r][1] = Abuf[n * 132 + 129];
        crd[r][2] = Abuf[n * 132 + 130];
    }
    #pragma unroll
    for (int ot = 0; ot < 8; ++ot) {
        const float4 wc = Wc0[ot * 16 + m];
        #pragma unroll
        for (int r = 0; r < 4; ++r) {
            const float v = acc0[ot][r] + wc.w + wc.x * crd[r][0] + wc.y * crd[r][1] + wc.z * crd[r][2];
            Bbuf[(wv * 16 + q * 4 + r) * 132 + ot * 16 + m] = fmaxf(v, 0.0f);
        }
    }
    __syncthreads();

    // layer 1: 128 -> 128
    f32x4 acc1[8];
    #pragma unroll
    for (int ot = 0; ot < 8; ++ot)
        #pragma unroll
        for (int r = 0; r < 4; ++r) acc1[ot][r] = 0.0f;
    #pragma unroll
    for (int ks = 0; ks < 4; ++ks) {
        float xv[8];
        *(float4*)&xv[0] = *(const float4*)&Bbuf[rowA * 132 + ks * 32 + q * 8];
        *(float4*)&xv[4] = *(const float4*)&Bbuf[rowA * 132 + ks * 32 + q * 8 + 4];
        SV8 ah, al;
        #pragma unroll
        for (int j = 0; j < 8; ++j) { ah.u[j] = f2bf(xv[j]); al.u[j] = f2bf(xv[j] - bf2f(ah.u[j])); }
        #pragma unroll
        for (int ot = 0; ot < 8; ++ot) {
            SV8 bh, bl;
            bh.v = *(const short8*)(W1h + (size_t)((ks * 8 + ot) * 64 + lane) * 8);
            bl.v = *(const short8*)(W1l + (size_t)((ks * 8 + ot) * 64 + lane) * 8);
            acc1[ot] = __builtin_amdgcn_mfma_f32_16x16x32_bf16(ah.v, bh.v, acc1[ot], 0, 0, 0);
            acc1[ot] = __builtin_amdgcn_mfma_f32_16x16x32_bf16(al.v, bh.v, acc1[ot], 0, 0, 0);
            acc1[ot] = __builtin_amdgcn_mfma_f32_16x16x32_bf16(ah.v, bl.v, acc1[ot], 0, 0, 0);
        }
    }
    __syncthreads();
    #pragma unroll
    for (int ot = 0; ot < 8; ++ot) {
        const float bb = b1[ot * 16 + m];
        #pragma unroll
        for (int r = 0; r < 4; ++r)
            Abuf[(wv * 16 + q * 4 + r) * 132 + ot * 16 + m] = fmaxf(acc1[ot][r] + bb, 0.0f);
    }
    __syncthreads();

    // layer 2: 128 -> 256, relu+max
    f32x4 acc2[16];
    #pragma unroll
    for (int ot = 0; ot < 16; ++ot)
        #pragma unroll
        for (int r = 0; r < 4; ++r) acc2[ot][r] = 0.0f;
    #pragma unroll
    for (int ks = 0; ks < 4; ++ks) {
        float xv[8];
        *(float4*)&xv[0] = *(const float4*)&Abuf[rowA * 132 + ks * 32 + q * 8];
        *(float4*)&xv[4] = *(const float4*)&Abuf[rowA * 132 + ks * 32 + q * 8 + 4];
        SV8 ah, al;
        #pragma unroll
        for (int j = 0; j < 8; ++j) { ah.u[j] = f2bf(xv[j]); al.u[j] = f2bf(xv[j] - bf2f(ah.u[j])); }
        #pragma unroll
        for (int ot = 0; ot < 16; ++ot) {
            SV8 bh, bl;
            bh.v = *(const short8*)(W2h + (size_t)((ks * 16 + ot) * 64 + lane) * 8);
            bl.v = *(const short8*)(W2l + (size_t)((ks * 16 + ot) * 64 + lane) * 8);
            acc2[ot] = __builtin_amdgcn_mfma_f32_16x16x32_bf16(ah.v, bh.v, acc2[ot], 0, 0, 0);
            acc2[ot] = __builtin_amdgcn_mfma_f32_16x16x32_bf16(al.v, bh.v, acc2[ot], 0, 0, 0);
            acc2[ot] = __builtin_amdgcn_mfma_f32_16x16x32_bf16(ah.v, bl.v, acc2[ot], 0, 0, 0);
        }
    }
    __syncthreads();
    #pragma unroll
    for (int ot = 0; ot < 16; ++ot) {
        const float bb = b2[ot * 16 + m];
        float mx = 0.0f;
        #pragma unroll
        for (int r = 0; r < 4; ++r) mx = fmaxf(mx, acc2[ot][r] + bb);
        Bbuf[(wv * 4 + q) * 256 + ot * 16 + m] = mx;
    }
    __syncthreads();
    {
        float v = Bbuf[t];
        #pragma unroll
        for (int rr = 1; rr < 16; ++rr) v = fmaxf(v, Bbuf[rr * 256 + t]);
        X3[(size_t)bs * 288 + 3 + t] = v;
    }
}

// ===================== stage-3 GEMM via MFMA (no LDS A) ====================
template<int KSTEPS, bool MAXOUT>
__global__ __launch_bounds__(256)
void gemm_mfma_kernel(const float* __restrict__ A, int AS,
                      const ushort* __restrict__ Wh, const ushort* __restrict__ Wl,
                      const float* __restrict__ bias, float* __restrict__ C, int O) {
    __shared__ float part[16][64];
    const int t = threadIdx.x, lane = t & 63, wv = t >> 6;
    const int m = lane & 15, q = lane >> 4;
    const int rowA = blockIdx.x * 64 + wv * 16 + m;
    const int bo = blockIdx.y, OT = O >> 4;
    f32x4 acc[4];
    #pragma unroll
    for (int ot = 0; ot < 4; ++ot)
        #pragma unroll
        for (int r = 0; r < 4; ++r) acc[ot][r] = 0.0f;
    for (int ks = 0; ks < KSTEPS; ++ks) {
        float xv[8];
        *(float4*)&xv[0] = *(const float4*)&A[(size_t)rowA * AS + ks * 32 + q * 8];
        *(float4*)&xv[4] = *(const float4*)&A[(size_t)rowA * AS + ks * 32 + q * 8 + 4];
        SV8 ah, al;
        #pragma unroll
        for (int j = 0; j < 8; ++j) { ah.u[j] = f2bf(xv[j]); al.u[j] = f2bf(xv[j] - bf2f(ah.u[j])); }
        #pragma unroll
        for (int ot = 0; ot < 4; ++ot) {
            const size_t wb = (size_t)((ks * OT + bo * 4 + ot) * 64 + lane) * 8;
            SV8 bh, bl;
            bh.v = *(const short8*)(Wh + wb);
            bl.v = *(const short8*)(Wl + wb);
            acc[ot] = __builtin_amdgcn_mfma_f32_16x16x32_bf16(ah.v, bh.v, acc[ot], 0, 0, 0);
            acc[ot] = __builtin_amdgcn_mfma_f32_16x16x32_bf16(al.v, bh.v, acc[ot], 0, 0, 0);
            acc[ot] = __builtin_amdgcn_mfma_f32_16x16x32_bf16(ah.v, bl.v, acc[ot], 0, 0, 0);
        }
    }
    if (!MAXOUT) {
        #pragma unroll
        for (int ot = 0; ot < 4; ++ot) {
            const int col = (bo * 4 + ot) * 16 + m;
            const float bb = bias[col];
            #pragma unroll
            for (int r = 0; r < 4; ++r) {
                const int row = blockIdx.x * 64 + wv * 16 + q * 4 + r;
                C[(size_t)row * O + col] = fmaxf(acc[ot][r] + bb, 0.0f);
            }
        }
    } else {
        #pragma unroll
        for (int ot = 0; ot < 4; ++ot) {
            const int col = (bo * 4 + ot) * 16 + m;
            const float bb = bias[col];
            float mx = 0.0f;
            #pragma unroll
            for (int r = 0; r < 4; ++r) mx = fmaxf(mx, acc[ot][r] + bb);
            part[wv * 4 + q][ot * 16 + m] = mx;
        }
        __syncthreads();
        if (t < 64) {
            float v = part[0][t];
            #pragma unroll
            for (int rr = 1; rr < 16; ++rr) v = fmaxf(v, part[rr][t]);
            C[(size_t)blockIdx.x * O + bo * 64 + t] = v;
        }
    }
}

// ============================ Generic fp32 GEMM (FC head) ==================
template<bool RELU>
__global__ __launch_bounds__(256)
void gemm_kernel(const float* __restrict__ A, const float* __restrict__ W,
                 const float* __restrict__ bias, float* __restrict__ C,
                 int M, int K, int O) {
    __shared__ __align__(16) float At[32*68];
    __shared__ __align__(16) float Wt[32*68];
    const int t = threadIdx.x;
    const int mtile = blockIdx.x * 64, otile = blockIdx.y * 64;
    const int tx = t & 15, ty = t >> 4;
    float acc[4][4];
    #pragma unroll
    for (int i = 0; i < 4; ++i)
        #pragma unroll
        for (int j = 0; j < 4; ++j) acc[i][j] = 0.0f;
    const int kk = t & 31, r0 = t >> 5;
    for (int k0 = 0; k0 < K; k0 += 32) {
        #pragma unroll
        for (int rr = 0; rr < 8; ++rr) {
            const int row = r0 + rr * 8;
            const int m = mtile + row, o = otile + row, k = k0 + kk;
            At[kk*68 + row] = (m < M && k < K) ? A[(size_t)m*K + k] : 0.0f;
            Wt[kk*68 + row] = (o < O && k < K) ? W[(size_t)o*K + k] : 0.0f;
        }
        __syncthreads();
        #pragma unroll
        for (int k2 = 0; k2 < 32; ++k2) {
            const float4 av = *(const float4*)&At[k2*68 + tx*4];
            const float4 wv = *(const float4*)&Wt[k2*68 + ty*4];
            const float a[4] = {av.x, av.y, av.z, av.w};
            const float w[4] = {wv.x, wv.y, wv.z, wv.w};
            #pragma unroll
            for (int i = 0; i < 4; ++i)
                #pragma unroll
                for (int j = 0; j < 4; ++j) acc[i][j] += a[i] * w[j];
        }
        __syncthreads();
    }
    #pragma unroll
    for (int i = 0; i < 4; ++i) {
        const int m = mtile + tx*4 + i;
        if (m >= M) continue;
        #pragma unroll
        for (int j = 0; j < 4; ++j) {
            const int o = otile + ty*4 + j;
            if (o >= O) continue;
            float v = acc[i][j] + bias[o];
            if (RELU) v = fmaxf(v, 0.0f);
            C[(size_t)m*O + o] = v;
        }
    }
}

// ============================ final max (P3 -> feat) =======================
__global__ __launch_bounds__(256)
void maxfin_kernel(const float* __restrict__ P3, float* __restrict__ feat) {
    const int idx = blockIdx.x * 256 + threadIdx.x;  // 32*1024
    const int b = idx >> 10, o = idx & 1023;
    feat[idx] = fmaxf(P3[(size_t)(2*b) * 1024 + o], P3[(size_t)(2*b+1) * 1024 + o]);
}

// ============================ launch =======================================
extern "C" void kernel_launch(void* const* d_in, const int* in_sizes, int n_in,
                              void* d_out, int out_size, void* d_ws, size_t ws_size,
                              hipStream_t stream) {
    const float* xyz  = (const float*)d_in[0];
    const float* s1w0 = (const float*)d_in[1];  const float* s1b0 = (const float*)d_in[2];
    const float* s1w1 = (const float*)d_in[3];  const float* s1b1 = (const float*)d_in[4];
    const float* s1w2 = (const float*)d_in[5];  const float* s1b2 = (const float*)d_in[6];
    const float* s2w0 = (const float*)d_in[7];  const float* s2b0 = (const float*)d_in[8];
    const float* s2w1 = (const float*)d_in[9];  const float* s2b1 = (const float*)d_in[10];
    const float* s2w2 = (const float*)d_in[11]; const float* s2b2 = (const float*)d_in[12];
    const float* s3w0 = (const float*)d_in[13]; const float* s3b0 = (const float*)d_in[14];
    const float* s3w1 = (const float*)d_in[15]; const float* s3b1 = (const float*)d_in[16];
    const float* s3w2 = (const float*)d_in[17]; const float* s3b2 = (const float*)d_in[18];
    const float* f1w  = (const float*)d_in[19]; const float* f1b  = (const float*)d_in[20];
    const float* f2w  = (const float*)d_in[21]; const float* f2b  = (const float*)d_in[22];
    const float* f3w  = (const float*)d_in[23]; const float* f3b  = (const float*)d_in[24];

    char* ws = (char*)d_ws;
    float* l1_xyz = (float*)(ws + 0);              // 32*512*3
    int*   gidx1  = (int*)  (ws + 196608);         // 32*512*32
    float* l1p    = (float*)(ws + 2293760);        // 32*512*128
    float* l2_xyz = (float*)(ws + 10682368);       // 32*128*3
    int*   gidx2  = (int*)  (ws + 10731520);       // 32*128*64
    float* X3p    = (float*)(ws + 11780096);       // 4096*288 (zero-padded)
    const size_t PK = 16498688;                    // pack region
    float4* Wc1   = (float4*)(ws + PK + 0);
    ushort* M1W1h = (ushort*)(ws + PK + 1024);
    ushort* M1W1l = (ushort*)(ws + PK + 9216);
    ushort* M1W2h = (ushort*)(ws + PK + 17408);
    ushort* M1W2l = (ushort*)(ws + PK + 33792);
    ushort* W0h   = (ushort*)(ws + PK + 50176);
    ushort* W0l   = (ushort*)(ws + PK + 82944);
    ushort* W1h   = (ushort*)(ws + PK + 115712);
    ushort* W1l   = (ushort*)(ws + PK + 148480);
    ushort* W2h   = (ushort*)(ws + PK + 181248);
    ushort* W2l   = (ushort*)(ws + PK + 246784);
    float4* Wc0   = (float4*)(ws + PK + 312320);
    ushort* S3W0h = (ushort*)(ws + PK + 314368);
    ushort* S3W0l = (ushort*)(ws + PK + 461824);
    ushort* S3W1h = (ushort*)(ws + PK + 609280);
    ushort* S3W1l = (ushort*)(ws + PK + 871424);
    ushort* S3W2h = (ushort*)(ws + PK + 1133568);
    ushort* S3W2l = (ushort*)(ws + PK + 2182144);
    float* Y1   = (float*)(ws + 19729408);         // 4096*256
    float* Y2   = (float*)(ws + 23923712);         // 4096*512
    float* P3   = (float*)(ws + 32312320);         // 64*1024 partial maxima
    float* feat = (float*)(ws + 32574464);         // 32*1024
    float* fb1  = (float*)(ws + 32705536);         // 32*512
    float* fb2  = (float*)(ws + 32771072);         // 32*256

    // Stage 1 (fps1 on blocks 0..31, weight pack on blocks 32..3185)
    fps1_prep_kernel<<<3186, 256, 0, stream>>>(xyz, l1_xyz,
        s1w0, s1b0, Wc1, s1w1, M1W1h, M1W1l, s1w2, M1W2h, M1W2l,
        s3w0, S3W0h, S3W0l, s3w1, S3W1h, S3W1l, s3w2, S3W2h, S3W2l,
        s2w0, s2b0, Wc0, W0h, W0l, s2w1, W1h, W1l, s2w2, W2h, W2l);
    bq_kernel<4096, 32, true, 1024><<<1024, 1024, 0, stream>>>(
        (float)(0.2 * 0.2), xyz, l1_xyz, gidx1, 512);
    {
        dim3 g(257, 32);   // x==256 -> fps2 for batch y
        mlp1_kernel<<<g, 256, 0, stream>>>(xyz, l1_xyz, l2_xyz, gidx1,
            Wc1, M1W1h, M1W1l, s1b1, M1W2h, M1W2l, s1b2, l1p);
    }

    // Stage 2
    bq_kernel<512, 64, false, 1024><<<256, 1024, 0, stream>>>(
        (float)(0.4 * 0.4), l1_xyz, l2_xyz, gidx2, 128);
    mlp2_kernel<<<4096, 256, 0, stream>>>(l1_xyz, l1p, l2_xyz, gidx2,
        W0h, W0l, Wc0, W1h, W1l, s2b1, W2h, W2l, s2b2, X3p);

    // Stage 3 (MFMA GEMMs; gemm3 fuses the 128-row max into P3)
    {
        dim3 g1(64, 4);
        gemm_mfma_kernel<9,  false><<<g1, 256, 0, stream>>>(X3p, 288, S3W0h, S3W0l, s3b0, Y1, 256);
        dim3 g2(64, 8);
        gemm_mfma_kernel<8,  false><<<g2, 256, 0, stream>>>(Y1, 256, S3W1h, S3W1l, s3b1, Y2, 512);
        dim3 g3(64, 16);
        gemm_mfma_kernel<16, true ><<<g3, 256, 0, stream>>>(Y2, 512, S3W2h, S3W2l, s3b2, P3, 1024);
    }
    maxfin_kernel<<<128, 256, 0, stream>>>(P3, feat);

    // FC head (fp32)
    {
        dim3 g1(1, 8); gemm_kernel<true><<<g1, 256, 0, stream>>>(feat, f1w, f1b, fb1, 32, 1024, 512);
        dim3 g2(1, 4); gemm_kernel<true><<<g2, 256, 0, stream>>>(fb1, f2w, f2b, fb2, 32, 512, 256);
        dim3 g3(1, 1); gemm_kernel<false><<<g3, 256, 0, stream>>>(fb2, f3w, f3b, (float*)d_out, 32, 256, 6);
    }
    (void)in_sizes; (void)n_in; (void)out_size; (void)ws_size;
}

// Round 11
// 973.321 us; speedup vs baseline: 1.6149x; 1.1176x over previous
//
#include <hip/hip_runtime.h>
#include <hip/hip_bf16.h>

// ---------------------------------------------------------------------------
// PointNet++ critic forward. B=32, N=4096.
// R11: (1) FPS barrier-free — tagged LDS mailbox ([tag8|dist32|idx12], parity
// slots, spin-poll) replaces per-iteration __syncthreads+drain. (2) FC head
// fused to one 32-block kernel (P3 row-max folded in); 4 launches removed.
// ---------------------------------------------------------------------------

typedef __attribute__((ext_vector_type(8))) short short8;
typedef __attribute__((ext_vector_type(4))) float f32x4;
union SV8 { short8 v; ushort u[8]; };

__device__ __forceinline__ ushort f2bf(float x) {
    unsigned u = __float_as_uint(x);
    unsigned r = (u + 0x7fffu + ((u >> 16) & 1u)) >> 16;   // RNE
    return (ushort)r;
}
__device__ __forceinline__ float bf2f(ushort h) {
    return __uint_as_float(((unsigned)h) << 16);
}

// ======================= DPP wave64 max-reduce (u64) =======================
template<int CTRL>
__device__ __forceinline__ unsigned long long dpp_mov_u64(unsigned long long x) {
    const int lo = (int)(unsigned)(x & 0xffffffffull);
    const int hi = (int)(unsigned)(x >> 32);
    const int nlo = __builtin_amdgcn_update_dpp(lo, lo, CTRL, 0xf, 0xf, false);
    const int nhi = __builtin_amdgcn_update_dpp(hi, hi, CTRL, 0xf, 0xf, false);
    return ((unsigned long long)(unsigned)nhi << 32) | (unsigned)nlo;
}

__device__ __forceinline__ unsigned long long wave_max_u64(unsigned long long x) {
    unsigned long long y;
    y = dpp_mov_u64<0x111>(x); if (y > x) x = y;   // row_shr:1
    y = dpp_mov_u64<0x112>(x); if (y > x) x = y;   // row_shr:2
    y = dpp_mov_u64<0x114>(x); if (y > x) x = y;   // row_shr:4
    y = dpp_mov_u64<0x118>(x); if (y > x) x = y;   // row_shr:8
    y = dpp_mov_u64<0x142>(x); if (y > x) x = y;   // row_bcast:15
    y = dpp_mov_u64<0x143>(x); if (y > x) x = y;   // row_bcast:31
    return x;
}

// ============================ FPS body =====================================
// smem layout: float4 sxyz[N]; u64 mailbox[2][NW] (tagged, barrier-free).
template<int N, int S, int NT, bool CHW>
__device__ __forceinline__ void fps_body(const float* __restrict__ xyz,
                                         float* __restrict__ new_xyz,
                                         int b, int t, char* smem) {
    constexpr int P  = N / NT;
    constexpr int NW = NT / 64;
    float4* sxyz = (float4*)smem;
    volatile unsigned long long* rv =
        (volatile unsigned long long*)(smem + (size_t)N * 16);
    float px[P], py[P], pz[P], dist[P];
    unsigned idc[P];
    if (CHW) {
        const float* base = xyz + (size_t)b * 3 * N;
        #pragma unroll
        for (int p = 0; p < P; ++p) {
            const int i = p * NT + t;
            px[p] = base[i]; py[p] = base[N + i]; pz[p] = base[2 * N + i];
            sxyz[i] = make_float4(px[p], py[p], pz[p], 0.0f);
        }
    } else {
        const float* base = xyz + (size_t)b * N * 3;
        #pragma unroll
        for (int p = 0; p < P; ++p) {
            const int i = p * NT + t;
            px[p] = base[i*3]; py[p] = base[i*3+1]; pz[p] = base[i*3+2];
            sxyz[i] = make_float4(px[p], py[p], pz[p], 0.0f);
        }
    }
    if (t < 2 * NW) rv[t] = 0xABull << 56;   // init tag: collides first at j=171 (long overwritten)
    #pragma unroll
    for (int p = 0; p < P; ++p) { dist[p] = 1e10f; idc[p] = (unsigned)(N - 1 - (p * NT + t)); }
    __syncthreads();                          // the only barrier (sxyz + mailbox init)
    int far = 0;
    float* out = new_xyz + (size_t)b * S * 3;
    for (int j = 0; j < S; ++j) {
        const float4 cen = sxyz[far];        // broadcast b128
        if (t == 0) { out[j*3+0] = cen.x; out[j*3+1] = cen.y; out[j*3+2] = cen.z; }
        unsigned long long pk[P];
        #pragma unroll
        for (int p = 0; p < P; ++p) {
            const float dx = px[p] - cen.x, dy = py[p] - cen.y, dz = pz[p] - cen.z;
            // match reference rounding exactly: no FMA contraction
            const float d = __fadd_rn(__fadd_rn(__fmul_rn(dx, dx), __fmul_rn(dy, dy)), __fmul_rn(dz, dz));
            const float nd = fminf(dist[p], d);
            dist[p] = nd;
            pk[p] = ((unsigned long long)__float_as_uint(nd) << 32) | idc[p];
        }
        #pragma unroll
        for (int s = P / 2; s > 0; s >>= 1)
            #pragma unroll
            for (int k = 0; k < s; ++k)
                if (pk[k + s] > pk[k]) pk[k] = pk[k + s];
        unsigned long long best = wave_max_u64(pk[0]);
        if constexpr (NW > 1) {
            const unsigned long long tagv = (unsigned long long)(j & 255);
            const int sl = (j & 1) * NW;
            if ((t & 63) == 63) {
                const unsigned long long db = best >> 32;          // dist bits
                const unsigned long long ix = best & 0xFFFull;     // idx (N<=4096)
                rv[sl + (t >> 6)] = (tagv << 56) | (db << 12) | ix;
            }
            unsigned long long vv[NW];
            for (;;) {
                #pragma unroll
                for (int w = 0; w < NW; ++w) vv[w] = rv[sl + w];   // batched ds_reads
                bool all = true;
                #pragma unroll
                for (int w = 0; w < NW; ++w) all &= ((vv[w] >> 56) == tagv);
                if (all) break;
            }
            unsigned long long bb = vv[0];
            #pragma unroll
            for (int w = 1; w < NW; ++w) if (vv[w] > bb) bb = vv[w];
            far = N - 1 - (int)(bb & 0xFFFull);
        } else {
            far = N - 1 - __builtin_amdgcn_readlane((int)(best & 0xffffffffull), 63);
        }
    }
}

// ==================== weight split + tile pack bodies ======================
__device__ __forceinline__ void packg(const float* __restrict__ src,
                                      ushort* __restrict__ dh, ushort* __restrict__ dl,
                                      int Ktot, int otiles, int cofs, int idx) {
    const int j = idx & 7, lane = (idx >> 3) & 63;
    const int ot = (idx >> 9) % otiles;
    const int ks = idx / (512 * otiles);
    const int m = lane & 15, q = lane >> 4;
    const int o = ot * 16 + m, c = cofs + ks * 32 + q * 8 + j;
    const float v = (c < Ktot) ? src[(size_t)o * Ktot + c] : 0.0f;
    const ushort h = f2bf(v);
    dh[idx] = h;
    dl[idx] = f2bf(v - bf2f(h));
}

// ================= fps1 + weight pack, merged launch =======================
__global__ __launch_bounds__(256)
void fps1_prep_kernel(const float* __restrict__ xyz, float* __restrict__ l1xyz,
                 const float* s1w0, const float* s1b0, float4* Wc1,
                 const float* s1w1, ushort* M1W1h, ushort* M1W1l,
                 const float* s1w2, ushort* M1W2h, ushort* M1W2l,
                 const float* s3w0, ushort* S3W0h, ushort* S3W0l,
                 const float* s3w1, ushort* S3W1h, ushort* S3W1l,
                 const float* s3w2, ushort* S3W2h, ushort* S3W2l,
                 const float* s2w0, const float* s2b0, float4* Wc0,
                 ushort* W0h, ushort* W0l,
                 const float* s2w1, ushort* W1h, ushort* W1l,
                 const float* s2w2, ushort* W2h, ushort* W2l) {
    __shared__ __align__(16) char smem[4096 * 16 + 64];
    if (blockIdx.x < 32) {
        fps_body<4096, 512, 256, true>(xyz, l1xyz, blockIdx.x, threadIdx.x, smem);
        return;
    }
    int i = (blockIdx.x - 32) * 256 + threadIdx.x;
    if (i < 64)     { Wc1[i] = make_float4(s1w0[i*3], s1w0[i*3+1], s1w0[i*3+2], s1b0[i]); return; }  i -= 64;
    if (i < 4096)   { packg(s1w1, M1W1h, M1W1l,  64,  4, 0, i); return; }   i -= 4096;
    if (i < 8192)   { packg(s1w2, M1W2h, M1W2l,  64,  8, 0, i); return; }   i -= 8192;
    if (i < 73728)  { packg(s3w0, S3W0h, S3W0l, 259, 16, 0, i); return; }   i -= 73728;
    if (i < 131072) { packg(s3w1, S3W1h, S3W1l, 256, 32, 0, i); return; }   i -= 131072;
    if (i < 524288) { packg(s3w2, S3W2h, S3W2l, 512, 64, 0, i); return; }   i -= 524288;
    if (i < 16384)  { packg(s2w0, W0h, W0l, 131,  8, 3, i); return; }       i -= 16384;
    if (i < 16384)  { packg(s2w1, W1h, W1l, 128,  8, 0, i); return; }       i -= 16384;
    if (i < 32768)  { packg(s2w2, W2h, W2l, 128, 16, 0, i); return; }       i -= 32768;
    if (i < 128) {
        Wc0[i] = make_float4(s2w0[(size_t)i*131+0], s2w0[(size_t)i*131+1],
                             s2w0[(size_t)i*131+2], s2b0[i]);
    }
}

// ============================ Ball query ===================================
template<int N, int NS, bool CHW, int NT>
__global__ __launch_bounds__(NT)
void bq_kernel(float r2, const float* __restrict__ xyz, const float* __restrict__ cen,
               int* __restrict__ gidx, int S) {
    constexpr int WPB = NT / 64;
    __shared__ __align__(16) float4 sp[N];
    const int t = threadIdx.x, lane = t & 63, w = t >> 6;
    const int cen0 = blockIdx.x * WPB;
    const int b = cen0 / S;                     // WPB divides S -> same batch
    if (CHW) {
        const float* base = xyz + (size_t)b * 3 * N;
        for (int i = t; i < N; i += NT)
            sp[i] = make_float4(base[i], base[N + i], base[2 * N + i], 0.0f);
    } else {
        const float* base = xyz + (size_t)b * N * 3;
        for (int i = t; i < N; i += NT)
            sp[i] = make_float4(base[i*3], base[i*3+1], base[i*3+2], 0.0f);
    }
    __syncthreads();
    const int wid = cen0 + w;
    const float cx = cen[(size_t)wid*3+0], cy = cen[(size_t)wid*3+1], cz = cen[(size_t)wid*3+2];
    int* out = gidx + (size_t)wid * NS;
    int cnt = 0, first = -1;
    for (int b0 = 0; b0 < N; b0 += 64) {
        const float4 p = sp[b0 + lane];
        const float dx = p.x - cx, dy = p.y - cy, dz = p.z - cz;
        const float d = __fadd_rn(__fadd_rn(__fmul_rn(dx, dx), __fmul_rn(dy, dy)), __fmul_rn(dz, dz));
        const bool in = (d <= r2);
        const unsigned long long m = __ballot(in);
        if (first < 0 && m != 0ull) first = b0 + __ffsll((unsigned long long)m) - 1;
        const int pos = cnt + (int)__popcll(m & ((1ull << lane) - 1ull));
        if (in && pos < NS) out[pos] = b0 + lane;
        cnt += (int)__popcll(m);
        if (cnt >= NS) break;
    }
    if (cnt < NS)
        for (int k = cnt + lane; k < NS; k += 64) out[k] = first;
}

// ==================== MLP stage 1 (MFMA) + fps2 merged =====================
__global__ __launch_bounds__(256)
void mlp1_kernel(const float* __restrict__ xyz, const float* __restrict__ l1xyz,
                 float* __restrict__ l2xyz,
                 const int* __restrict__ gidx, const float4* __restrict__ Wc1,
                 const ushort* __restrict__ W1h, const ushort* __restrict__ W1l,
                 const float* __restrict__ b1,
                 const ushort* __restrict__ W2h, const ushort* __restrict__ W2l,
                 const float* __restrict__ b2,
                 float* __restrict__ l1p) {
    __shared__ __align__(16) char smem[64 * 68 * 4 * 2];   // 34816 B
    float* bufA = (float*)smem;                  // h0, later max-partials
    float* bufB = (float*)(smem + 64 * 68 * 4);  // g, later h1
    const int t = threadIdx.x, b = blockIdx.y;
    if (blockIdx.x == 256) {   // fps2 (needs only l1xyz; 8256 B of smem)
        fps_body<512, 128, 256, false>(l1xyz, l2xyz, b, t, smem);
        return;
    }
    const int s0 = blockIdx.x * 2;
    {
        const int n = t >> 2, c = t & 3;
        const int s = s0 + (n >> 5);
        const int gi = gidx[((size_t)b * 512 + s) * 32 + (n & 31)];
        float v = 0.0f;
        if (c < 3) v = xyz[(size_t)b * 3 * 4096 + c * 4096 + gi] - l1xyz[((size_t)b * 512 + s) * 3 + c];
        bufB[n * 4 + c] = v;
    }
    __syncthreads();
    {   // layer0: 3 -> 64, exact fp32
        const int o = t & 63, ng = t >> 6;
        const float4 wc = Wc1[o];
        #pragma unroll
        for (int r = 0; r < 16; ++r) {
            const int n = ng * 16 + r;
            const float z = wc.w + wc.x * bufB[n*4] + wc.y * bufB[n*4+1] + wc.z * bufB[n*4+2];
            bufA[n * 68 + o] = fmaxf(z, 0.0f);
        }
    }
    const int lane = t & 63, wv = t >> 6;
    const int m = lane & 15, q = lane >> 4;
    const int rowA = wv * 16 + m;
    // layer1: 64 -> 64 (2 ksteps, 4 otiles)  [wave-private h0 band]
    f32x4 acc1[4];
    #pragma unroll
    for (int ot = 0; ot < 4; ++ot)
        #pragma unroll
        for (int r = 0; r < 4; ++r) acc1[ot][r] = 0.0f;
    #pragma unroll
    for (int ks = 0; ks < 2; ++ks) {
        float xv[8];
        *(float4*)&xv[0] = *(const float4*)&bufA[rowA * 68 + ks * 32 + q * 8];
        *(float4*)&xv[4] = *(const float4*)&bufA[rowA * 68 + ks * 32 + q * 8 + 4];
        SV8 ah, al;
        #pragma unroll
        for (int j = 0; j < 8; ++j) { ah.u[j] = f2bf(xv[j]); al.u[j] = f2bf(xv[j] - bf2f(ah.u[j])); }
        #pragma unroll
        for (int ot = 0; ot < 4; ++ot) {
            SV8 bh, bl;
            bh.v = *(const short8*)(W1h + (size_t)((ks * 4 + ot) * 64 + lane) * 8);
            bl.v = *(const short8*)(W1l + (size_t)((ks * 4 + ot) * 64 + lane) * 8);
            acc1[ot] = __builtin_amdgcn_mfma_f32_16x16x32_bf16(ah.v, bh.v, acc1[ot], 0, 0, 0);
            acc1[ot] = __builtin_amdgcn_mfma_f32_16x16x32_bf16(al.v, bh.v, acc1[ot], 0, 0, 0);
            acc1[ot] = __builtin_amdgcn_mfma_f32_16x16x32_bf16(ah.v, bl.v, acc1[ot], 0, 0, 0);
        }
    }
    #pragma unroll
    for (int ot = 0; ot < 4; ++ot) {
        const float bb = b1[ot * 16 + m];
        #pragma unroll
        for (int r = 0; r < 4; ++r)
            bufB[(wv * 16 + q * 4 + r) * 68 + ot * 16 + m] = fmaxf(acc1[ot][r] + bb, 0.0f);
    }
    // layer2: 64 -> 128 (2 ksteps, 8 otiles) + per-wave max  [wave-private]
    f32x4 acc2[8];
    #pragma unroll
    for (int ot = 0; ot < 8; ++ot)
        #pragma unroll
        for (int r = 0; r < 4; ++r) acc2[ot][r] = 0.0f;
    #pragma unroll
    for (int ks = 0; ks < 2; ++ks) {
        float xv[8];
        *(float4*)&xv[0] = *(const float4*)&bufB[rowA * 68 + ks * 32 + q * 8];
        *(float4*)&xv[4] = *(const float4*)&bufB[rowA * 68 + ks * 32 + q * 8 + 4];
        SV8 ah, al;
        #pragma unroll
        for (int j = 0; j < 8; ++j) { ah.u[j] = f2bf(xv[j]); al.u[j] = f2bf(xv[j] - bf2f(ah.u[j])); }
        #pragma unroll
        for (int ot = 0; ot < 8; ++ot) {
            SV8 bh, bl;
            bh.v = *(const short8*)(W2h + (size_t)((ks * 8 + ot) * 64 + lane) * 8);
            bl.v = *(const short8*)(W2l + (size_t)((ks * 8 + ot) * 64 + lane) * 8);
            acc2[ot] = __builtin_amdgcn_mfma_f32_16x16x32_bf16(ah.v, bh.v, acc2[ot], 0, 0, 0);
            acc2[ot] = __builtin_amdgcn_mfma_f32_16x16x32_bf16(al.v, bh.v, acc2[ot], 0, 0, 0);
            acc2[ot] = __builtin_amdgcn_mfma_f32_16x16x32_bf16(ah.v, bl.v, acc2[ot], 0, 0, 0);
        }
    }
    __syncthreads();
    #pragma unroll
    for (int ot = 0; ot < 8; ++ot) {
        const float bb = b2[ot * 16 + m];
        float mx = 0.0f;
        #pragma unroll
        for (int r = 0; r < 4; ++r) mx = fmaxf(mx, acc2[ot][r] + bb);
        bufA[(wv * 4 + q) * 128 + ot * 16 + m] = mx;
    }
    __syncthreads();
    {
        const int half = t >> 7, o = t & 127;
        float v = bufA[(half * 8) * 128 + o];
        #pragma unroll
        for (int rr = 1; rr < 8; ++rr) v = fmaxf(v, bufA[(half * 8 + rr) * 128 + o]);
        l1p[((size_t)b * 512 + s0 + half) * 128 + o] = v;
    }
}

// ============================ MLP stage 2 (MFMA) ===========================
__global__ __launch_bounds__(256)
void mlp2_kernel(const float* __restrict__ l1xyz, const float* __restrict__ l1p,
                 const float* __restrict__ l2xyz, const int* __restrict__ gidx,
                 const ushort* __restrict__ W0h, const ushort* __restrict__ W0l,
                 const float4* __restrict__ Wc0,
                 const ushort* __restrict__ W1h, const ushort* __restrict__ W1l,
                 const float* __restrict__ b1,
                 const ushort* __restrict__ W2h, const ushort* __restrict__ W2l,
                 const float* __restrict__ b2,
                 float* __restrict__ X3) {
    __shared__ __align__(16) float Abuf[64 * 132];   // x / h2
    __shared__ __align__(16) float Bbuf[64 * 132];   // h1 / max-partials
    __shared__ int sg[64];
    const int t = threadIdx.x, bs = blockIdx.x, b = bs >> 7;
    if (t < 64) sg[t] = gidx[(size_t)bs * 64 + t];
    if (t < 3)  X3[(size_t)bs * 288 + t] = l2xyz[(size_t)bs * 3 + t];     // raw coords
    if (t >= 64 && t < 93) X3[(size_t)bs * 288 + 259 + (t - 64)] = 0.0f;  // zero pad
    __syncthreads();
    for (int i = t; i < 64 * 32; i += 256) {
        const int n = i >> 5, cc = i & 31;
        *(float4*)&Abuf[n * 132 + cc * 4] =
            *(const float4*)&l1p[((size_t)b * 512 + sg[n]) * 128 + cc * 4];
    }
    if (t < 192) {
        const int n = t / 3, c = t % 3;
        Abuf[n * 132 + 128 + c] =
            l1xyz[((size_t)b * 512 + sg[n]) * 3 + c] - l2xyz[(size_t)bs * 3 + c];
    }
    __syncthreads();
    const int lane = t & 63, wv = t >> 6;
    const int m = lane & 15, q = lane >> 4;
    const int rowA = wv * 16 + m;

    // layer 0: feats (K=128) MFMA + coords/bias epilogue
    f32x4 acc0[8];
    #pragma unroll
    for (int ot = 0; ot < 8; ++ot)
        #pragma unroll
        for (int r = 0; r < 4; ++r) acc0[ot][r] = 0.0f;
    #pragma unroll
    for (int ks = 0; ks < 4; ++ks) {
        float xv[8];
        *(float4*)&xv[0] = *(const float4*)&Abuf[rowA * 132 + ks * 32 + q * 8];
        *(float4*)&xv[4] = *(const float4*)&Abuf[rowA * 132 + ks * 32 + q * 8 + 4];
        SV8 ah, al;
        #pragma unroll
        for (int j = 0; j < 8; ++j) { ah.u[j] = f2bf(xv[j]); al.u[j] = f2bf(xv[j] - bf2f(ah.u[j])); }
        #pragma unroll
        for (int ot = 0; ot < 8; ++ot) {
            SV8 bh, bl;
            bh.v = *(const short8*)(W0h + (size_t)((ks * 8 + ot) * 64 + lane) * 8);
            bl.v = *(const short8*)(W0l + (size_t)((ks * 8 + ot) * 64 + lane) * 8);
            acc0[ot] = __builtin_amdgcn_mfma_f32_16x16x32_bf16(ah.v, bh.v, acc0[ot], 0, 0, 0);
            acc0[ot] = __builtin_amdgcn_mfma_f32_16x16x32_bf16(al.v, bh.v, acc0[ot], 0, 0, 0);
            acc0[ot] = __builtin_amdgcn_mfma_f32_16x16x32_bf16(ah.v, bl.v, acc0[ot], 0, 0, 0);
        }
    }
    float crd[4][3];
    #pragma unroll
    for (int r = 0; r < 4; ++r) {
        const int n = wv * 16 + q * 4 + r;
        crd[r][0] = Abuf[n * 132 + 128];
        crd[r][1] = Abuf[n * 132 + 129];
        crd[r][2] = Abuf[n * 132 + 130];
    }
    #pragma unroll
    for (int ot = 0; ot < 8; ++ot) {
        const float4 wc = Wc0[ot * 16 + m];
        #pragma unroll
        for (int r = 0; r < 4; ++r) {
            const float v = acc0[ot][r] + wc.w + wc.x * crd[r][0] + wc.y * crd[r][1] + wc.z * crd[r][2];
            Bbuf[(wv * 16 + q * 4 + r) * 132 + ot * 16 + m] = fmaxf(v, 0.0f);
        }
    }
    __syncthreads();

    // layer 1: 128 -> 128
    f32x4 acc1[8];
    #pragma unroll
    for (int ot = 0; ot < 8; ++ot)
        #pragma unroll
        for (int r = 0; r < 4; ++r) acc1[ot][r] = 0.0f;
    #pragma unroll
    for (int ks = 0; ks < 4; ++ks) {
        float xv[8];
        *(float4*)&xv[0] = *(const float4*)&Bbuf[rowA * 132 + ks * 32 + q * 8];
        *(float4*)&xv[4] = *(const float4*)&Bbuf[rowA * 132 + ks * 32 + q * 8 + 4];
        SV8 ah, al;
        #pragma unroll
        for (int j = 0; j < 8; ++j) { ah.u[j] = f2bf(xv[j]); al.u[j] = f2bf(xv[j] - bf2f(ah.u[j])); }
        #pragma unroll
        for (int ot = 0; ot < 8; ++ot) {
            SV8 bh, bl;
            bh.v = *(const short8*)(W1h + (size_t)((ks * 8 + ot) * 64 + lane) * 8);
            bl.v = *(const short8*)(W1l + (size_t)((ks * 8 + ot) * 64 + lane) * 8);
            acc1[ot] = __builtin_amdgcn_mfma_f32_16x16x32_bf16(ah.v, bh.v, acc1[ot], 0, 0, 0);
            acc1[ot] = __builtin_amdgcn_mfma_f32_16x16x32_bf16(al.v, bh.v, acc1[ot], 0, 0, 0);
            acc1[ot] = __builtin_amdgcn_mfma_f32_16x16x32_bf16(ah.v, bl.v, acc1[ot], 0, 0, 0);
        }
    }
    __syncthreads();
    #pragma unroll
    for (int ot = 0; ot < 8; ++ot) {
        const float bb = b1[ot * 16 + m];
        #pragma unroll
        for (int r = 0; r < 4; ++r)
            Abuf[(wv * 16 + q * 4 + r) * 132 + ot * 16 + m] = fmaxf(acc1[ot][r] + bb, 0.0f);
    }
    __syncthreads();

    // layer 2: 128 -> 256, relu+max
    f32x4 acc2[16];
    #pragma unroll
    for (int ot = 0; ot < 16; ++ot)
        #pragma unroll
        for (int r = 0; r < 4; ++r) acc2[ot][r] = 0.0f;
    #pragma unroll
    for (int ks = 0; ks < 4; ++ks) {
        float xv[8];
        *(float4*)&xv[0] = *(const float4*)&Abuf[rowA * 132 + ks * 32 + q * 8];
        *(float4*)&xv[4] = *(const float4*)&Abuf[rowA * 132 + ks * 32 + q * 8 + 4];
        SV8 ah, al;
        #pragma unroll
        for (int j = 0; j < 8; ++j) { ah.u[j] = f2bf(xv[j]); al.u[j] = f2bf(xv[j] - bf2f(ah.u[j])); }
        #pragma unroll
        for (int ot = 0; ot < 16; ++ot) {
            SV8 bh, bl;
            bh.v = *(const short8*)(W2h + (size_t)((ks * 16 + ot) * 64 + lane) * 8);
            bl.v = *(const short8*)(W2l + (size_t)((ks * 16 + ot) * 64 + lane) * 8);
            acc2[ot] = __builtin_amdgcn_mfma_f32_16x16x32_bf16(ah.v, bh.v, acc2[ot], 0, 0, 0);
            acc2[ot] = __builtin_amdgcn_mfma_f32_16x16x32_bf16(al.v, bh.v, acc2[ot], 0, 0, 0);
            acc2[ot] = __builtin_amdgcn_mfma_f32_16x16x32_bf16(ah.v, bl.v, acc2[ot], 0, 0, 0);
        }
    }
    __syncthreads();
    #pragma unroll
    for (int ot = 0; ot < 16; ++ot) {
        const float bb = b2[ot * 16 + m];
        float mx = 0.0f;
        #pragma unroll
        for (int r = 0; r < 4; ++r) mx = fmaxf(mx, acc2[ot][r] + bb);
        Bbuf[(wv * 4 + q) * 256 + ot * 16 + m] = mx;
    }
    __syncthreads();
    {
        float v = Bbuf[t];
        #pragma unroll
        for (int rr = 1; rr < 16; ++rr) v = fmaxf(v, Bbuf[rr * 256 + t]);
        X3[(size_t)bs * 288 + 3 + t] = v;
    }
}

// ===================== stage-3 GEMM via MFMA (no LDS A) ====================
template<int KSTEPS, bool MAXOUT>
__global__ __launch_bounds__(256)
void gemm_mfma_kernel(const float* __restrict__ A, int AS,
                      const ushort* __restrict__ Wh, const ushort* __restrict__ Wl,
                      const float* __restrict__ bias, float* __restrict__ C, int O) {
    __shared__ float part[16][64];
    const int t = threadIdx.x, lane = t & 63, wv = t >> 6;
    const int m = lane & 15, q = lane >> 4;
    const int rowA = blockIdx.x * 64 + wv * 16 + m;
    const int bo = blockIdx.y, OT = O >> 4;
    f32x4 acc[4];
    #pragma unroll
    for (int ot = 0; ot < 4; ++ot)
        #pragma unroll
        for (int r = 0; r < 4; ++r) acc[ot][r] = 0.0f;
    for (int ks = 0; ks < KSTEPS; ++ks) {
        float xv[8];
        *(float4*)&xv[0] = *(const float4*)&A[(size_t)rowA * AS + ks * 32 + q * 8];
        *(float4*)&xv[4] = *(const float4*)&A[(size_t)rowA * AS + ks * 32 + q * 8 + 4];
        SV8 ah, al;
        #pragma unroll
        for (int j = 0; j < 8; ++j) { ah.u[j] = f2bf(xv[j]); al.u[j] = f2bf(xv[j] - bf2f(ah.u[j])); }
        #pragma unroll
        for (int ot = 0; ot < 4; ++ot) {
            const size_t wb = (size_t)((ks * OT + bo * 4 + ot) * 64 + lane) * 8;
            SV8 bh, bl;
            bh.v = *(const short8*)(Wh + wb);
            bl.v = *(const short8*)(Wl + wb);
            acc[ot] = __builtin_amdgcn_mfma_f32_16x16x32_bf16(ah.v, bh.v, acc[ot], 0, 0, 0);
            acc[ot] = __builtin_amdgcn_mfma_f32_16x16x32_bf16(al.v, bh.v, acc[ot], 0, 0, 0);
            acc[ot] = __builtin_amdgcn_mfma_f32_16x16x32_bf16(ah.v, bl.v, acc[ot], 0, 0, 0);
        }
    }
    if (!MAXOUT) {
        #pragma unroll
        for (int ot = 0; ot < 4; ++ot) {
            const int col = (bo * 4 + ot) * 16 + m;
            const float bb = bias[col];
            #pragma unroll
            for (int r = 0; r < 4; ++r) {
                const int row = blockIdx.x * 64 + wv * 16 + q * 4 + r;
                C[(size_t)row * O + col] = fmaxf(acc[ot][r] + bb, 0.0f);
            }
        }
    } else {
        #pragma unroll
        for (int ot = 0; ot < 4; ++ot) {
            const int col = (bo * 4 + ot) * 16 + m;
            const float bb = bias[col];
            float mx = 0.0f;
            #pragma unroll
            for (int r = 0; r < 4; ++r) mx = fmaxf(mx, acc[ot][r] + bb);
            part[wv * 4 + q][ot * 16 + m] = mx;
        }
        __syncthreads();
        if (t < 64) {
            float v = part[0][t];
            #pragma unroll
            for (int rr = 1; rr < 16; ++rr) v = fmaxf(v, part[rr][t]);
            C[(size_t)blockIdx.x * O + bo * 64 + t] = v;
        }
    }
}

// ================= fused FC head (P3 row-max + 3 layers) ===================
// 32 blocks (one per batch row) x 256 threads.
__global__ __launch_bounds__(256)
void fchead_kernel(const float* __restrict__ P3,
                   const float* __restrict__ f1w, const float* __restrict__ f1b,
                   const float* __restrict__ f2w, const float* __restrict__ f2b,
                   const float* __restrict__ f3w, const float* __restrict__ f3b,
                   float* __restrict__ out) {
    __shared__ __align__(16) float x[1024];
    __shared__ __align__(16) float h1[512];
    __shared__ __align__(16) float h2[256];
    const int t = threadIdx.x, b = blockIdx.x;
    for (int i = t; i < 1024; i += 256)
        x[i] = fmaxf(P3[(size_t)(2*b)*1024 + i], P3[(size_t)(2*b+1)*1024 + i]);
    __syncthreads();
    #pragma unroll
    for (int oo = 0; oo < 2; ++oo) {       // f1: 1024 -> 512
        const int o = t + oo * 256;
        const float4* wr = (const float4*)(f1w + (size_t)o * 1024);
        float s0 = 0, s1 = 0, s2 = 0, s3 = 0;
        for (int c = 0; c < 256; ++c) {
            const float4 w4 = wr[c];
            const float4 xv = *(const float4*)&x[c * 4];
            s0 += w4.x * xv.x; s1 += w4.y * xv.y; s2 += w4.z * xv.z; s3 += w4.w * xv.w;
        }
        h1[o] = fmaxf(f1b[o] + ((s0 + s1) + (s2 + s3)), 0.0f);
    }
    __syncthreads();
    {                                       // f2: 512 -> 256
        const float4* wr = (const float4*)(f2w + (size_t)t * 512);
        float s0 = 0, s1 = 0, s2 = 0, s3 = 0;
        for (int c = 0; c < 128; ++c) {
            const float4 w4 = wr[c];
            const float4 xv = *(const float4*)&h1[c * 4];
            s0 += w4.x * xv.x; s1 += w4.y * xv.y; s2 += w4.z * xv.z; s3 += w4.w * xv.w;
        }
        h2[t] = fmaxf(f2b[t] + ((s0 + s1) + (s2 + s3)), 0.0f);
    }
    __syncthreads();
    if (t < 6) {                            // f3: 256 -> 6
        const float4* wr = (const float4*)(f3w + (size_t)t * 256);
        float s0 = 0, s1 = 0, s2 = 0, s3 = 0;
        for (int c = 0; c < 64; ++c) {
            const float4 w4 = wr[c];
            const float4 xv = *(const float4*)&h2[c * 4];
            s0 += w4.x * xv.x; s1 += w4.y * xv.y; s2 += w4.z * xv.z; s3 += w4.w * xv.w;
        }
        out[b * 6 + t] = f3b[t] + ((s0 + s1) + (s2 + s3));
    }
}

// ============================ launch =======================================
extern "C" void kernel_launch(void* const* d_in, const int* in_sizes, int n_in,
                              void* d_out, int out_size, void* d_ws, size_t ws_size,
                              hipStream_t stream) {
    const float* xyz  = (const float*)d_in[0];
    const float* s1w0 = (const float*)d_in[1];  const float* s1b0 = (const float*)d_in[2];
    const float* s1w1 = (const float*)d_in[3];  const float* s1b1 = (const float*)d_in[4];
    const float* s1w2 = (const float*)d_in[5];  const float* s1b2 = (const float*)d_in[6];
    const float* s2w0 = (const float*)d_in[7];  const float* s2b0 = (const float*)d_in[8];
    const float* s2w1 = (const float*)d_in[9];  const float* s2b1 = (const float*)d_in[10];
    const float* s2w2 = (const float*)d_in[11]; const float* s2b2 = (const float*)d_in[12];
    const float* s3w0 = (const float*)d_in[13]; const float* s3b0 = (const float*)d_in[14];
    const float* s3w1 = (const float*)d_in[15]; const float* s3b1 = (const float*)d_in[16];
    const float* s3w2 = (const float*)d_in[17]; const float* s3b2 = (const float*)d_in[18];
    const float* f1w  = (const float*)d_in[19]; const float* f1b  = (const float*)d_in[20];
    const float* f2w  = (const float*)d_in[21]; const float* f2b  = (const float*)d_in[22];
    const float* f3w  = (const float*)d_in[23]; const float* f3b  = (const float*)d_in[24];

    char* ws = (char*)d_ws;
    float* l1_xyz = (float*)(ws + 0);              // 32*512*3
    int*   gidx1  = (int*)  (ws + 196608);         // 32*512*32
    float* l1p    = (float*)(ws + 2293760);        // 32*512*128
    float* l2_xyz = (float*)(ws + 10682368);       // 32*128*3
    int*   gidx2  = (int*)  (ws + 10731520);       // 32*128*64
    float* X3p    = (float*)(ws + 11780096);       // 4096*288 (zero-padded)
    const size_t PK = 16498688;                    // pack region
    float4* Wc1   = (float4*)(ws + PK + 0);
    ushort* M1W1h = (ushort*)(ws + PK + 1024);
    ushort* M1W1l = (ushort*)(ws + PK + 9216);
    ushort* M1W2h = (ushort*)(ws + PK + 17408);
    ushort* M1W2l = (ushort*)(ws + PK + 33792);
    ushort* W0h   = (ushort*)(ws + PK + 50176);
    ushort* W0l   = (ushort*)(ws + PK + 82944);
    ushort* W1h   = (ushort*)(ws + PK + 115712);
    ushort* W1l   = (ushort*)(ws + PK + 148480);
    ushort* W2h   = (ushort*)(ws + PK + 181248);
    ushort* W2l   = (ushort*)(ws + PK + 246784);
    float4* Wc0   = (float4*)(ws + PK + 312320);
    ushort* S3W0h = (ushort*)(ws + PK + 314368);
    ushort* S3W0l = (ushort*)(ws + PK + 461824);
    ushort* S3W1h = (ushort*)(ws + PK + 609280);
    ushort* S3W1l = (ushort*)(ws + PK + 871424);
    ushort* S3W2h = (ushort*)(ws + PK + 1133568);
    ushort* S3W2l = (ushort*)(ws + PK + 2182144);
    float* Y1   = (float*)(ws + 19729408);         // 4096*256
    float* Y2   = (float*)(ws + 23923712);         // 4096*512
    float* P3   = (float*)(ws + 32312320);         // 64*1024 partial maxima
    // (feat/fb1/fb2 folded into fchead_kernel LDS)

    // Stage 1 (fps1 on blocks 0..31, weight pack on blocks 32..3185)
    fps1_prep_kernel<<<3186, 256, 0, stream>>>(xyz, l1_xyz,
        s1w0, s1b0, Wc1, s1w1, M1W1h, M1W1l, s1w2, M1W2h, M1W2l,
        s3w0, S3W0h, S3W0l, s3w1, S3W1h, S3W1l, s3w2, S3W2h, S3W2l,
        s2w0, s2b0, Wc0, W0h, W0l, s2w1, W1h, W1l, s2w2, W2h, W2l);
    bq_kernel<4096, 32, true, 1024><<<1024, 1024, 0, stream>>>(
        (float)(0.2 * 0.2), xyz, l1_xyz, gidx1, 512);
    {
        dim3 g(257, 32);   // x==256 -> fps2 for batch y
        mlp1_kernel<<<g, 256, 0, stream>>>(xyz, l1_xyz, l2_xyz, gidx1,
            Wc1, M1W1h, M1W1l, s1b1, M1W2h, M1W2l, s1b2, l1p);
    }

    // Stage 2
    bq_kernel<512, 64, false, 1024><<<256, 1024, 0, stream>>>(
        (float)(0.4 * 0.4), l1_xyz, l2_xyz, gidx2, 128);
    mlp2_kernel<<<4096, 256, 0, stream>>>(l1_xyz, l1p, l2_xyz, gidx2,
        W0h, W0l, Wc0, W1h, W1l, s2b1, W2h, W2l, s2b2, X3p);

    // Stage 3 (MFMA GEMMs; gemm3 fuses the 128-row max into P3)
    {
        dim3 g1(64, 4);
        gemm_mfma_kernel<9,  false><<<g1, 256, 0, stream>>>(X3p, 288, S3W0h, S3W0l, s3b0, Y1, 256);
        dim3 g2(64, 8);
        gemm_mfma_kernel<8,  false><<<g2, 256, 0, stream>>>(Y1, 256, S3W1h, S3W1l, s3b1, Y2, 512);
        dim3 g3(64, 16);
        gemm_mfma_kernel<16, true ><<<g3, 256, 0, stream>>>(Y2, 512, S3W2h, S3W2l, s3b2, P3, 1024);
    }

    // Fused FC head (row-max of P3 + 1024->512->256->6)
    fchead_kernel<<<32, 256, 0, stream>>>(P3, f1w, f1b, f2w, f2b, f3w, f3b, (float*)d_out);
    (void)in_sizes; (void)n_in; (void)out_size; (void)ws_size;
}

// Round 12
// 900.121 us; speedup vs baseline: 1.7462x; 1.0813x over previous
//
#include <hip/hip_runtime.h>
#include <hip/hip_bf16.h>

// ---------------------------------------------------------------------------
// PointNet++ critic forward. B=32, N=4096.
// R12: FPS = R10 parity-slot + syncthreads exchange (mailbox reverted), with
// ALL global stores deferred out of the loop (sfar[] in LDS, cooperative
// writeback at end) so the per-iteration barrier's vmcnt(0) drain is free.
// ---------------------------------------------------------------------------

typedef __attribute__((ext_vector_type(8))) short short8;
typedef __attribute__((ext_vector_type(4))) float f32x4;
union SV8 { short8 v; ushort u[8]; };

__device__ __forceinline__ ushort f2bf(float x) {
    unsigned u = __float_as_uint(x);
    unsigned r = (u + 0x7fffu + ((u >> 16) & 1u)) >> 16;   // RNE
    return (ushort)r;
}
__device__ __forceinline__ float bf2f(ushort h) {
    return __uint_as_float(((unsigned)h) << 16);
}

// ======================= DPP wave64 max-reduce (u64) =======================
template<int CTRL>
__device__ __forceinline__ unsigned long long dpp_mov_u64(unsigned long long x) {
    const int lo = (int)(unsigned)(x & 0xffffffffull);
    const int hi = (int)(unsigned)(x >> 32);
    const int nlo = __builtin_amdgcn_update_dpp(lo, lo, CTRL, 0xf, 0xf, false);
    const int nhi = __builtin_amdgcn_update_dpp(hi, hi, CTRL, 0xf, 0xf, false);
    return ((unsigned long long)(unsigned)nhi << 32) | (unsigned)nlo;
}

__device__ __forceinline__ unsigned long long wave_max_u64(unsigned long long x) {
    unsigned long long y;
    y = dpp_mov_u64<0x111>(x); if (y > x) x = y;   // row_shr:1
    y = dpp_mov_u64<0x112>(x); if (y > x) x = y;   // row_shr:2
    y = dpp_mov_u64<0x114>(x); if (y > x) x = y;   // row_shr:4
    y = dpp_mov_u64<0x118>(x); if (y > x) x = y;   // row_shr:8
    y = dpp_mov_u64<0x142>(x); if (y > x) x = y;   // row_bcast:15
    y = dpp_mov_u64<0x143>(x); if (y > x) x = y;   // row_bcast:31
    return x;
}

// ============================ FPS body =====================================
// smem: float4 sxyz[N]; u64 rv[2*NW]; int sfar[S]. No global ops in the loop.
template<int N, int S, int NT, bool CHW>
__device__ __forceinline__ void fps_body(const float* __restrict__ xyz,
                                         float* __restrict__ new_xyz,
                                         int b, int t, char* smem) {
    constexpr int P  = N / NT;
    constexpr int NW = NT / 64;
    float4* sxyz = (float4*)smem;
    unsigned long long* rv = (unsigned long long*)(smem + (size_t)N * 16);
    int* sfar = (int*)(smem + (size_t)N * 16 + 2 * NW * 8);
    float px[P], py[P], pz[P], dist[P];
    unsigned idc[P];
    if (CHW) {
        const float* base = xyz + (size_t)b * 3 * N;
        #pragma unroll
        for (int p = 0; p < P; ++p) {
            const int i = p * NT + t;
            px[p] = base[i]; py[p] = base[N + i]; pz[p] = base[2 * N + i];
            sxyz[i] = make_float4(px[p], py[p], pz[p], 0.0f);
        }
    } else {
        const float* base = xyz + (size_t)b * N * 3;
        #pragma unroll
        for (int p = 0; p < P; ++p) {
            const int i = p * NT + t;
            px[p] = base[i*3]; py[p] = base[i*3+1]; pz[p] = base[i*3+2];
            sxyz[i] = make_float4(px[p], py[p], pz[p], 0.0f);
        }
    }
    #pragma unroll
    for (int p = 0; p < P; ++p) { dist[p] = 1e10f; idc[p] = (unsigned)(N - 1 - (p * NT + t)); }
    __syncthreads();
    int far = 0;
    for (int j = 0; j < S; ++j) {
        if (t == 0) sfar[j] = far;           // LDS only — no VMEM in loop
        const float4 cen = sxyz[far];        // broadcast b128
        unsigned long long pk[P];
        #pragma unroll
        for (int p = 0; p < P; ++p) {
            const float dx = px[p] - cen.x, dy = py[p] - cen.y, dz = pz[p] - cen.z;
            // match reference rounding exactly: no FMA contraction
            const float d = __fadd_rn(__fadd_rn(__fmul_rn(dx, dx), __fmul_rn(dy, dy)), __fmul_rn(dz, dz));
            const float nd = fminf(dist[p], d);
            dist[p] = nd;
            pk[p] = ((unsigned long long)__float_as_uint(nd) << 32) | idc[p];
        }
        #pragma unroll
        for (int s = P / 2; s > 0; s >>= 1)
            #pragma unroll
            for (int k = 0; k < s; ++k)
                if (pk[k + s] > pk[k]) pk[k] = pk[k + s];
        unsigned long long best = wave_max_u64(pk[0]);
        if constexpr (NW > 1) {
            const int sl = (j & 1) * NW;     // parity slots: overwrite-safe
            if ((t & 63) == 63) rv[sl + (t >> 6)] = best;
            __syncthreads();
            unsigned long long bb = rv[sl];
            #pragma unroll
            for (int w = 1; w < NW; ++w) { const unsigned long long v = rv[sl + w]; if (v > bb) bb = v; }
            far = N - 1 - (int)(bb & 0xffffffffull);
        } else {
            far = N - 1 - __builtin_amdgcn_readlane((int)(best & 0xffffffffull), 63);
        }
    }
    __syncthreads();
    // cooperative writeback of all S centroids
    float* out = new_xyz + (size_t)b * S * 3;
    for (int i = t; i < S; i += NT) {
        const float4 c = sxyz[sfar[i]];
        out[i*3+0] = c.x; out[i*3+1] = c.y; out[i*3+2] = c.z;
    }
}

// ==================== weight split + tile pack bodies ======================
__device__ __forceinline__ void packg(const float* __restrict__ src,
                                      ushort* __restrict__ dh, ushort* __restrict__ dl,
                                      int Ktot, int otiles, int cofs, int idx) {
    const int j = idx & 7, lane = (idx >> 3) & 63;
    const int ot = (idx >> 9) % otiles;
    const int ks = idx / (512 * otiles);
    const int m = lane & 15, q = lane >> 4;
    const int o = ot * 16 + m, c = cofs + ks * 32 + q * 8 + j;
    const float v = (c < Ktot) ? src[(size_t)o * Ktot + c] : 0.0f;
    const ushort h = f2bf(v);
    dh[idx] = h;
    dl[idx] = f2bf(v - bf2f(h));
}

// ================= fps1 + weight pack, merged launch =======================
__global__ __launch_bounds__(256)
void fps1_prep_kernel(const float* __restrict__ xyz, float* __restrict__ l1xyz,
                 const float* s1w0, const float* s1b0, float4* Wc1,
                 const float* s1w1, ushort* M1W1h, ushort* M1W1l,
                 const float* s1w2, ushort* M1W2h, ushort* M1W2l,
                 const float* s3w0, ushort* S3W0h, ushort* S3W0l,
                 const float* s3w1, ushort* S3W1h, ushort* S3W1l,
                 const float* s3w2, ushort* S3W2h, ushort* S3W2l,
                 const float* s2w0, const float* s2b0, float4* Wc0,
                 ushort* W0h, ushort* W0l,
                 const float* s2w1, ushort* W1h, ushort* W1l,
                 const float* s2w2, ushort* W2h, ushort* W2l) {
    __shared__ __align__(16) char smem[4096 * 16 + 64 + 512 * 4];
    if (blockIdx.x < 32) {
        fps_body<4096, 512, 256, true>(xyz, l1xyz, blockIdx.x, threadIdx.x, smem);
        return;
    }
    int i = (blockIdx.x - 32) * 256 + threadIdx.x;
    if (i < 64)     { Wc1[i] = make_float4(s1w0[i*3], s1w0[i*3+1], s1w0[i*3+2], s1b0[i]); return; }  i -= 64;
    if (i < 4096)   { packg(s1w1, M1W1h, M1W1l,  64,  4, 0, i); return; }   i -= 4096;
    if (i < 8192)   { packg(s1w2, M1W2h, M1W2l,  64,  8, 0, i); return; }   i -= 8192;
    if (i < 73728)  { packg(s3w0, S3W0h, S3W0l, 259, 16, 0, i); return; }   i -= 73728;
    if (i < 131072) { packg(s3w1, S3W1h, S3W1l, 256, 32, 0, i); return; }   i -= 131072;
    if (i < 524288) { packg(s3w2, S3W2h, S3W2l, 512, 64, 0, i); return; }   i -= 524288;
    if (i < 16384)  { packg(s2w0, W0h, W0l, 131,  8, 3, i); return; }       i -= 16384;
    if (i < 16384)  { packg(s2w1, W1h, W1l, 128,  8, 0, i); return; }       i -= 16384;
    if (i < 32768)  { packg(s2w2, W2h, W2l, 128, 16, 0, i); return; }       i -= 32768;
    if (i < 128) {
        Wc0[i] = make_float4(s2w0[(size_t)i*131+0], s2w0[(size_t)i*131+1],
                             s2w0[(size_t)i*131+2], s2b0[i]);
    }
}

// ============================ Ball query ===================================
template<int N, int NS, bool CHW, int NT>
__global__ __launch_bounds__(NT)
void bq_kernel(float r2, const float* __restrict__ xyz, const float* __restrict__ cen,
               int* __restrict__ gidx, int S) {
    constexpr int WPB = NT / 64;
    __shared__ __align__(16) float4 sp[N];
    const int t = threadIdx.x, lane = t & 63, w = t >> 6;
    const int cen0 = blockIdx.x * WPB;
    const int b = cen0 / S;                     // WPB divides S -> same batch
    if (CHW) {
        const float* base = xyz + (size_t)b * 3 * N;
        for (int i = t; i < N; i += NT)
            sp[i] = make_float4(base[i], base[N + i], base[2 * N + i], 0.0f);
    } else {
        const float* base = xyz + (size_t)b * N * 3;
        for (int i = t; i < N; i += NT)
            sp[i] = make_float4(base[i*3], base[i*3+1], base[i*3+2], 0.0f);
    }
    __syncthreads();
    const int wid = cen0 + w;
    const float cx = cen[(size_t)wid*3+0], cy = cen[(size_t)wid*3+1], cz = cen[(size_t)wid*3+2];
    int* out = gidx + (size_t)wid * NS;
    int cnt = 0, first = -1;
    for (int b0 = 0; b0 < N; b0 += 64) {
        const float4 p = sp[b0 + lane];
        const float dx = p.x - cx, dy = p.y - cy, dz = p.z - cz;
        const float d = __fadd_rn(__fadd_rn(__fmul_rn(dx, dx), __fmul_rn(dy, dy)), __fmul_rn(dz, dz));
        const bool in = (d <= r2);
        const unsigned long long m = __ballot(in);
        if (first < 0 && m != 0ull) first = b0 + __ffsll((unsigned long long)m) - 1;
        const int pos = cnt + (int)__popcll(m & ((1ull << lane) - 1ull));
        if (in && pos < NS) out[pos] = b0 + lane;
        cnt += (int)__popcll(m);
        if (cnt >= NS) break;
    }
    if (cnt < NS)
        for (int k = cnt + lane; k < NS; k += 64) out[k] = first;
}

// ==================== MLP stage 1 (MFMA) + fps2 merged =====================
__global__ __launch_bounds__(256)
void mlp1_kernel(const float* __restrict__ xyz, const float* __restrict__ l1xyz,
                 float* __restrict__ l2xyz,
                 const int* __restrict__ gidx, const float4* __restrict__ Wc1,
                 const ushort* __restrict__ W1h, const ushort* __restrict__ W1l,
                 const float* __restrict__ b1,
                 const ushort* __restrict__ W2h, const ushort* __restrict__ W2l,
                 const float* __restrict__ b2,
                 float* __restrict__ l1p) {
    __shared__ __align__(16) char smem[64 * 68 * 4 * 2];   // 34816 B
    float* bufA = (float*)smem;                  // h0, later max-partials
    float* bufB = (float*)(smem + 64 * 68 * 4);  // g, later h1
    const int t = threadIdx.x, b = blockIdx.y;
    if (blockIdx.x == 256) {   // fps2 (needs only l1xyz; ~8.8 KB of smem)
        fps_body<512, 128, 256, false>(l1xyz, l2xyz, b, t, smem);
        return;
    }
    const int s0 = blockIdx.x * 2;
    {
        const int n = t >> 2, c = t & 3;
        const int s = s0 + (n >> 5);
        const int gi = gidx[((size_t)b * 512 + s) * 32 + (n & 31)];
        float v = 0.0f;
        if (c < 3) v = xyz[(size_t)b * 3 * 4096 + c * 4096 + gi] - l1xyz[((size_t)b * 512 + s) * 3 + c];
        bufB[n * 4 + c] = v;
    }
    __syncthreads();
    {   // layer0: 3 -> 64, exact fp32
        const int o = t & 63, ng = t >> 6;
        const float4 wc = Wc1[o];
        #pragma unroll
        for (int r = 0; r < 16; ++r) {
            const int n = ng * 16 + r;
            const float z = wc.w + wc.x * bufB[n*4] + wc.y * bufB[n*4+1] + wc.z * bufB[n*4+2];
            bufA[n * 68 + o] = fmaxf(z, 0.0f);
        }
    }
    const int lane = t & 63, wv = t >> 6;
    const int m = lane & 15, q = lane >> 4;
    const int rowA = wv * 16 + m;
    // layer1: 64 -> 64 (2 ksteps, 4 otiles)  [wave-private h0 band]
    f32x4 acc1[4];
    #pragma unroll
    for (int ot = 0; ot < 4; ++ot)
        #pragma unroll
        for (int r = 0; r < 4; ++r) acc1[ot][r] = 0.0f;
    #pragma unroll
    for (int ks = 0; ks < 2; ++ks) {
        float xv[8];
        *(float4*)&xv[0] = *(const float4*)&bufA[rowA * 68 + ks * 32 + q * 8];
        *(float4*)&xv[4] = *(const float4*)&bufA[rowA * 68 + ks * 32 + q * 8 + 4];
        SV8 ah, al;
        #pragma unroll
        for (int j = 0; j < 8; ++j) { ah.u[j] = f2bf(xv[j]); al.u[j] = f2bf(xv[j] - bf2f(ah.u[j])); }
        #pragma unroll
        for (int ot = 0; ot < 4; ++ot) {
            SV8 bh, bl;
            bh.v = *(const short8*)(W1h + (size_t)((ks * 4 + ot) * 64 + lane) * 8);
            bl.v = *(const short8*)(W1l + (size_t)((ks * 4 + ot) * 64 + lane) * 8);
            acc1[ot] = __builtin_amdgcn_mfma_f32_16x16x32_bf16(ah.v, bh.v, acc1[ot], 0, 0, 0);
            acc1[ot] = __builtin_amdgcn_mfma_f32_16x16x32_bf16(al.v, bh.v, acc1[ot], 0, 0, 0);
            acc1[ot] = __builtin_amdgcn_mfma_f32_16x16x32_bf16(ah.v, bl.v, acc1[ot], 0, 0, 0);
        }
    }
    #pragma unroll
    for (int ot = 0; ot < 4; ++ot) {
        const float bb = b1[ot * 16 + m];
        #pragma unroll
        for (int r = 0; r < 4; ++r)
            bufB[(wv * 16 + q * 4 + r) * 68 + ot * 16 + m] = fmaxf(acc1[ot][r] + bb, 0.0f);
    }
    // layer2: 64 -> 128 (2 ksteps, 8 otiles) + per-wave max  [wave-private]
    f32x4 acc2[8];
    #pragma unroll
    for (int ot = 0; ot < 8; ++ot)
        #pragma unroll
        for (int r = 0; r < 4; ++r) acc2[ot][r] = 0.0f;
    #pragma unroll
    for (int ks = 0; ks < 2; ++ks) {
        float xv[8];
        *(float4*)&xv[0] = *(const float4*)&bufB[rowA * 68 + ks * 32 + q * 8];
        *(float4*)&xv[4] = *(const float4*)&bufB[rowA * 68 + ks * 32 + q * 8 + 4];
        SV8 ah, al;
        #pragma unroll
        for (int j = 0; j < 8; ++j) { ah.u[j] = f2bf(xv[j]); al.u[j] = f2bf(xv[j] - bf2f(ah.u[j])); }
        #pragma unroll
        for (int ot = 0; ot < 8; ++ot) {
            SV8 bh, bl;
            bh.v = *(const short8*)(W2h + (size_t)((ks * 8 + ot) * 64 + lane) * 8);
            bl.v = *(const short8*)(W2l + (size_t)((ks * 8 + ot) * 64 + lane) * 8);
            acc2[ot] = __builtin_amdgcn_mfma_f32_16x16x32_bf16(ah.v, bh.v, acc2[ot], 0, 0, 0);
            acc2[ot] = __builtin_amdgcn_mfma_f32_16x16x32_bf16(al.v, bh.v, acc2[ot], 0, 0, 0);
            acc2[ot] = __builtin_amdgcn_mfma_f32_16x16x32_bf16(ah.v, bl.v, acc2[ot], 0, 0, 0);
        }
    }
    __syncthreads();
    #pragma unroll
    for (int ot = 0; ot < 8; ++ot) {
        const float bb = b2[ot * 16 + m];
        float mx = 0.0f;
        #pragma unroll
        for (int r = 0; r < 4; ++r) mx = fmaxf(mx, acc2[ot][r] + bb);
        bufA[(wv * 4 + q) * 128 + ot * 16 + m] = mx;
    }
    __syncthreads();
    {
        const int half = t >> 7, o = t & 127;
        float v = bufA[(half * 8) * 128 + o];
        #pragma unroll
        for (int rr = 1; rr < 8; ++rr) v = fmaxf(v, bufA[(half * 8 + rr) * 128 + o]);
        l1p[((size_t)b * 512 + s0 + half) * 128 + o] = v;
    }
}

// ============================ MLP stage 2 (MFMA) ===========================
__global__ __launch_bounds__(256)
void mlp2_kernel(const float* __restrict__ l1xyz, const float* __restrict__ l1p,
                 const float* __restrict__ l2xyz, const int* __restrict__ gidx,
                 const ushort* __restrict__ W0h, const ushort* __restrict__ W0l,
                 const float4* __restrict__ Wc0,
                 const ushort* __restrict__ W1h, const ushort* __restrict__ W1l,
                 const float* __restrict__ b1,
                 const ushort* __restrict__ W2h, const ushort* __restrict__ W2l,
                 const float* __restrict__ b2,
                 float* __restrict__ X3) {
    __shared__ __align__(16) float Abuf[64 * 132];   // x / h2
    __shared__ __align__(16) float Bbuf[64 * 132];   // h1 / max-partials
    __shared__ int sg[64];
    const int t = threadIdx.x, bs = blockIdx.x, b = bs >> 7;
    if (t < 64) sg[t] = gidx[(size_t)bs * 64 + t];
    if (t < 3)  X3[(size_t)bs * 288 + t] = l2xyz[(size_t)bs * 3 + t];     // raw coords
    if (t >= 64 && t < 93) X3[(size_t)bs * 288 + 259 + (t - 64)] = 0.0f;  // zero pad
    __syncthreads();
    for (int i = t; i < 64 * 32; i += 256) {
        const int n = i >> 5, cc = i & 31;
        *(float4*)&Abuf[n * 132 + cc * 4] =
            *(const float4*)&l1p[((size_t)b * 512 + sg[n]) * 128 + cc * 4];
    }
    if (t < 192) {
        const int n = t / 3, c = t % 3;
        Abuf[n * 132 + 128 + c] =
            l1xyz[((size_t)b * 512 + sg[n]) * 3 + c] - l2xyz[(size_t)bs * 3 + c];
    }
    __syncthreads();
    const int lane = t & 63, wv = t >> 6;
    const int m = lane & 15, q = lane >> 4;
    const int rowA = wv * 16 + m;

    // layer 0: feats (K=128) MFMA + coords/bias epilogue
    f32x4 acc0[8];
    #pragma unroll
    for (int ot = 0; ot < 8; ++ot)
        #pragma unroll
        for (int r = 0; r < 4; ++r) acc0[ot][r] = 0.0f;
    #pragma unroll
    for (int ks = 0; ks < 4; ++ks) {
        float xv[8];
        *(float4*)&xv[0] = *(const float4*)&Abuf[rowA * 132 + ks * 32 + q * 8];
        *(float4*)&xv[4] = *(const float4*)&Abuf[rowA * 132 + ks * 32 + q * 8 + 4];
        SV8 ah, al;
        #pragma unroll
        for (int j = 0; j < 8; ++j) { ah.u[j] = f2bf(xv[j]); al.u[j] = f2bf(xv[j] - bf2f(ah.u[j])); }
        #pragma unroll
        for (int ot = 0; ot < 8; ++ot) {
            SV8 bh, bl;
            bh.v = *(const short8*)(W0h + (size_t)((ks * 8 + ot) * 64 + lane) * 8);
            bl.v = *(const short8*)(W0l + (size_t)((ks * 8 + ot) * 64 + lane) * 8);
            acc0[ot] = __builtin_amdgcn_mfma_f32_16x16x32_bf16(ah.v, bh.v, acc0[ot], 0, 0, 0);
            acc0[ot] = __builtin_amdgcn_mfma_f32_16x16x32_bf16(al.v, bh.v, acc0[ot], 0, 0, 0);
            acc0[ot] = __builtin_amdgcn_mfma_f32_16x16x32_bf16(ah.v, bl.v, acc0[ot], 0, 0, 0);
        }
    }
    float crd[4][3];
    #pragma unroll
    for (int r = 0; r < 4; ++r) {
        const int n = wv * 16 + q * 4 + r;
        crd[r][0] = Abuf[n * 132 + 128];
        crd[r][1] = Abuf[n * 132 + 129];
        crd[r][2] = Abuf[n * 132 + 130];
    }
    #pragma unroll
    for (int ot = 0; ot < 8; ++ot) {
        const float4 wc = Wc0[ot * 16 + m];
        #pragma unroll
        for (int r = 0; r < 4; ++r) {
            const float v = acc0[ot][r] + wc.w + wc.x * crd[r][0] + wc.y * crd[r][1] + wc.z * crd[r][2];
            Bbuf[(wv * 16 + q * 4 + r) * 132 + ot * 16 + m] = fmaxf(v, 0.0f);
        }
    }
    __syncthreads();

    // layer 1: 128 -> 128
    f32x4 acc1[8];
    #pragma unroll
    for (int ot = 0; ot < 8; ++ot)
        #pragma unroll
        for (int r = 0; r < 4; ++r) acc1[ot][r] = 0.0f;
    #pragma unroll
    for (int ks = 0; ks < 4; ++ks) {
        float xv[8];
        *(float4*)&xv[0] = *(const float4*)&Bbuf[rowA * 132 + ks * 32 + q * 8];
        *(float4*)&xv[4] = *(const float4*)&Bbuf[rowA * 132 + ks * 32 + q * 8 + 4];
        SV8 ah, al;
        #pragma unroll
        for (int j = 0; j < 8; ++j) { ah.u[j] = f2bf(xv[j]); al.u[j] = f2bf(xv[j] - bf2f(ah.u[j])); }
        #pragma unroll
        for (int ot = 0; ot < 8; ++ot) {
            SV8 bh, bl;
            bh.v = *(const short8*)(W1h + (size_t)((ks * 8 + ot) * 64 + lane) * 8);
            bl.v = *(const short8*)(W1l + (size_t)((ks * 8 + ot) * 64 + lane) * 8);
            acc1[ot] = __builtin_amdgcn_mfma_f32_16x16x32_bf16(ah.v, bh.v, acc1[ot], 0, 0, 0);
            acc1[ot] = __builtin_amdgcn_mfma_f32_16x16x32_bf16(al.v, bh.v, acc1[ot], 0, 0, 0);
            acc1[ot] = __builtin_amdgcn_mfma_f32_16x16x32_bf16(ah.v, bl.v, acc1[ot], 0, 0, 0);
        }
    }
    __syncthreads();
    #pragma unroll
    for (int ot = 0; ot < 8; ++ot) {
        const float bb = b1[ot * 16 + m];
        #pragma unroll
        for (int r = 0; r < 4; ++r)
            Abuf[(wv * 16 + q * 4 + r) * 132 + ot * 16 + m] = fmaxf(acc1[ot][r] + bb, 0.0f);
    }
    __syncthreads();

    // layer 2: 128 -> 256, relu+max
    f32x4 acc2[16];
    #pragma unroll
    for (int ot = 0; ot < 16; ++ot)
        #pragma unroll
        for (int r = 0; r < 4; ++r) acc2[ot][r] = 0.0f;
    #pragma unroll
    for (int ks = 0; ks < 4; ++ks) {
        float xv[8];
        *(float4*)&xv[0] = *(const float4*)&Abuf[rowA * 132 + ks * 32 + q * 8];
        *(float4*)&xv[4] = *(const float4*)&Abuf[rowA * 132 + ks * 32 + q * 8 + 4];
        SV8 ah, al;
        #pragma unroll
        for (int j = 0; j < 8; ++j) { ah.u[j] = f2bf(xv[j]); al.u[j] = f2bf(xv[j] - bf2f(ah.u[j])); }
        #pragma unroll
        for (int ot = 0; ot < 16; ++ot) {
            SV8 bh, bl;
            bh.v = *(const short8*)(W2h + (size_t)((ks * 16 + ot) * 64 + lane) * 8);
            bl.v = *(const short8*)(W2l + (size_t)((ks * 16 + ot) * 64 + lane) * 8);
            acc2[ot] = __builtin_amdgcn_mfma_f32_16x16x32_bf16(ah.v, bh.v, acc2[ot], 0, 0, 0);
            acc2[ot] = __builtin_amdgcn_mfma_f32_16x16x32_bf16(al.v, bh.v, acc2[ot], 0, 0, 0);
            acc2[ot] = __builtin_amdgcn_mfma_f32_16x16x32_bf16(ah.v, bl.v, acc2[ot], 0, 0, 0);
        }
    }
    __syncthreads();
    #pragma unroll
    for (int ot = 0; ot < 16; ++ot) {
        const float bb = b2[ot * 16 + m];
        float mx = 0.0f;
        #pragma unroll
        for (int r = 0; r < 4; ++r) mx = fmaxf(mx, acc2[ot][r] + bb);
        Bbuf[(wv * 4 + q) * 256 + ot * 16 + m] = mx;
    }
    __syncthreads();
    {
        float v = Bbuf[t];
        #pragma unroll
        for (int rr = 1; rr < 16; ++rr) v = fmaxf(v, Bbuf[rr * 256 + t]);
        X3[(size_t)bs * 288 + 3 + t] = v;
    }
}

// ===================== stage-3 GEMM via MFMA (no LDS A) ====================
template<int KSTEPS, bool MAXOUT>
__global__ __launch_bounds__(256)
void gemm_mfma_kernel(const float* __restrict__ A, int AS,
                      const ushort* __restrict__ Wh, const ushort* __restrict__ Wl,
                      const float* __restrict__ bias, float* __restrict__ C, int O) {
    __shared__ float part[16][64];
    const int t = threadIdx.x, lane = t & 63, wv = t >> 6;
    const int m = lane & 15, q = lane >> 4;
    const int rowA = blockIdx.x * 64 + wv * 16 + m;
    const int bo = blockIdx.y, OT = O >> 4;
    f32x4 acc[4];
    #pragma unroll
    for (int ot = 0; ot < 4; ++ot)
        #pragma unroll
        for (int r = 0; r < 4; ++r) acc[ot][r] = 0.0f;
    for (int ks = 0; ks < KSTEPS; ++ks) {
        float xv[8];
        *(float4*)&xv[0] = *(const float4*)&A[(size_t)rowA * AS + ks * 32 + q * 8];
        *(float4*)&xv[4] = *(const float4*)&A[(size_t)rowA * AS + ks * 32 + q * 8 + 4];
        SV8 ah, al;
        #pragma unroll
        for (int j = 0; j < 8; ++j) { ah.u[j] = f2bf(xv[j]); al.u[j] = f2bf(xv[j] - bf2f(ah.u[j])); }
        #pragma unroll
        for (int ot = 0; ot < 4; ++ot) {
            const size_t wb = (size_t)((ks * OT + bo * 4 + ot) * 64 + lane) * 8;
            SV8 bh, bl;
            bh.v = *(const short8*)(Wh + wb);
            bl.v = *(const short8*)(Wl + wb);
            acc[ot] = __builtin_amdgcn_mfma_f32_16x16x32_bf16(ah.v, bh.v, acc[ot], 0, 0, 0);
            acc[ot] = __builtin_amdgcn_mfma_f32_16x16x32_bf16(al.v, bh.v, acc[ot], 0, 0, 0);
            acc[ot] = __builtin_amdgcn_mfma_f32_16x16x32_bf16(ah.v, bl.v, acc[ot], 0, 0, 0);
        }
    }
    if (!MAXOUT) {
        #pragma unroll
        for (int ot = 0; ot < 4; ++ot) {
            const int col = (bo * 4 + ot) * 16 + m;
            const float bb = bias[col];
            #pragma unroll
            for (int r = 0; r < 4; ++r) {
                const int row = blockIdx.x * 64 + wv * 16 + q * 4 + r;
                C[(size_t)row * O + col] = fmaxf(acc[ot][r] + bb, 0.0f);
            }
        }
    } else {
        #pragma unroll
        for (int ot = 0; ot < 4; ++ot) {
            const int col = (bo * 4 + ot) * 16 + m;
            const float bb = bias[col];
            float mx = 0.0f;
            #pragma unroll
            for (int r = 0; r < 4; ++r) mx = fmaxf(mx, acc[ot][r] + bb);
            part[wv * 4 + q][ot * 16 + m] = mx;
        }
        __syncthreads();
        if (t < 64) {
            float v = part[0][t];
            #pragma unroll
            for (int rr = 1; rr < 16; ++rr) v = fmaxf(v, part[rr][t]);
            C[(size_t)blockIdx.x * O + bo * 64 + t] = v;
        }
    }
}

// ================= fused FC head (P3 row-max + 3 layers) ===================
__global__ __launch_bounds__(256)
void fchead_kernel(const float* __restrict__ P3,
                   const float* __restrict__ f1w, const float* __restrict__ f1b,
                   const float* __restrict__ f2w, const float* __restrict__ f2b,
                   const float* __restrict__ f3w, const float* __restrict__ f3b,
                   float* __restrict__ out) {
    __shared__ __align__(16) float x[1024];
    __shared__ __align__(16) float h1[512];
    __shared__ __align__(16) float h2[256];
    const int t = threadIdx.x, b = blockIdx.x;
    for (int i = t; i < 1024; i += 256)
        x[i] = fmaxf(P3[(size_t)(2*b)*1024 + i], P3[(size_t)(2*b+1)*1024 + i]);
    __syncthreads();
    #pragma unroll
    for (int oo = 0; oo < 2; ++oo) {       // f1: 1024 -> 512
        const int o = t + oo * 256;
        const float4* wr = (const float4*)(f1w + (size_t)o * 1024);
        float s0 = 0, s1 = 0, s2 = 0, s3 = 0;
        for (int c = 0; c < 256; ++c) {
            const float4 w4 = wr[c];
            const float4 xv = *(const float4*)&x[c * 4];
            s0 += w4.x * xv.x; s1 += w4.y * xv.y; s2 += w4.z * xv.z; s3 += w4.w * xv.w;
        }
        h1[o] = fmaxf(f1b[o] + ((s0 + s1) + (s2 + s3)), 0.0f);
    }
    __syncthreads();
    {                                       // f2: 512 -> 256
        const float4* wr = (const float4*)(f2w + (size_t)t * 512);
        float s0 = 0, s1 = 0, s2 = 0, s3 = 0;
        for (int c = 0; c < 128; ++c) {
            const float4 w4 = wr[c];
            const float4 xv = *(const float4*)&h1[c * 4];
            s0 += w4.x * xv.x; s1 += w4.y * xv.y; s2 += w4.z * xv.z; s3 += w4.w * xv.w;
        }
        h2[t] = fmaxf(f2b[t] + ((s0 + s1) + (s2 + s3)), 0.0f);
    }
    __syncthreads();
    if (t < 6) {                            // f3: 256 -> 6
        const float4* wr = (const float4*)(f3w + (size_t)t * 256);
        float s0 = 0, s1 = 0, s2 = 0, s3 = 0;
        for (int c = 0; c < 64; ++c) {
            const float4 w4 = wr[c];
            const float4 xv = *(const float4*)&h2[c * 4];
            s0 += w4.x * xv.x; s1 += w4.y * xv.y; s2 += w4.z * xv.z; s3 += w4.w * xv.w;
        }
        out[b * 6 + t] = f3b[t] + ((s0 + s1) + (s2 + s3));
    }
}

// ============================ launch =======================================
extern "C" void kernel_launch(void* const* d_in, const int* in_sizes, int n_in,
                              void* d_out, int out_size, void* d_ws, size_t ws_size,
                              hipStream_t stream) {
    const float* xyz  = (const float*)d_in[0];
    const float* s1w0 = (const float*)d_in[1];  const float* s1b0 = (const float*)d_in[2];
    const float* s1w1 = (const float*)d_in[3];  const float* s1b1 = (const float*)d_in[4];
    const float* s1w2 = (const float*)d_in[5];  const float* s1b2 = (const float*)d_in[6];
    const float* s2w0 = (const float*)d_in[7];  const float* s2b0 = (const float*)d_in[8];
    const float* s2w1 = (const float*)d_in[9];  const float* s2b1 = (const float*)d_in[10];
    const float* s2w2 = (const float*)d_in[11]; const float* s2b2 = (const float*)d_in[12];
    const float* s3w0 = (const float*)d_in[13]; const float* s3b0 = (const float*)d_in[14];
    const float* s3w1 = (const float*)d_in[15]; const float* s3b1 = (const float*)d_in[16];
    const float* s3w2 = (const float*)d_in[17]; const float* s3b2 = (const float*)d_in[18];
    const float* f1w  = (const float*)d_in[19]; const float* f1b  = (const float*)d_in[20];
    const float* f2w  = (const float*)d_in[21]; const float* f2b  = (const float*)d_in[22];
    const float* f3w  = (const float*)d_in[23]; const float* f3b  = (const float*)d_in[24];

    char* ws = (char*)d_ws;
    float* l1_xyz = (float*)(ws + 0);              // 32*512*3
    int*   gidx1  = (int*)  (ws + 196608);         // 32*512*32
    float* l1p    = (float*)(ws + 2293760);        // 32*512*128
    float* l2_xyz = (float*)(ws + 10682368);       // 32*128*3
    int*   gidx2  = (int*)  (ws + 10731520);       // 32*128*64
    float* X3p    = (float*)(ws + 11780096);       // 4096*288 (zero-padded)
    const size_t PK = 16498688;                    // pack region
    float4* Wc1   = (float4*)(ws + PK + 0);
    ushort* M1W1h = (ushort*)(ws + PK + 1024);
    ushort* M1W1l = (ushort*)(ws + PK + 9216);
    ushort* M1W2h = (ushort*)(ws + PK + 17408);
    ushort* M1W2l = (ushort*)(ws + PK + 33792);
    ushort* W0h   = (ushort*)(ws + PK + 50176);
    ushort* W0l   = (ushort*)(ws + PK + 82944);
    ushort* W1h   = (ushort*)(ws + PK + 115712);
    ushort* W1l   = (ushort*)(ws + PK + 148480);
    ushort* W2h   = (ushort*)(ws + PK + 181248);
    ushort* W2l   = (ushort*)(ws + PK + 246784);
    float4* Wc0   = (float4*)(ws + PK + 312320);
    ushort* S3W0h = (ushort*)(ws + PK + 314368);
    ushort* S3W0l = (ushort*)(ws + PK + 461824);
    ushort* S3W1h = (ushort*)(ws + PK + 609280);
    ushort* S3W1l = (ushort*)(ws + PK + 871424);
    ushort* S3W2h = (ushort*)(ws + PK + 1133568);
    ushort* S3W2l = (ushort*)(ws + PK + 2182144);
    float* Y1   = (float*)(ws + 19729408);         // 4096*256
    float* Y2   = (float*)(ws + 23923712);         // 4096*512
    float* P3   = (float*)(ws + 32312320);         // 64*1024 partial maxima

    // Stage 1 (fps1 on blocks 0..31, weight pack on blocks 32..3185)
    fps1_prep_kernel<<<3186, 256, 0, stream>>>(xyz, l1_xyz,
        s1w0, s1b0, Wc1, s1w1, M1W1h, M1W1l, s1w2, M1W2h, M1W2l,
        s3w0, S3W0h, S3W0l, s3w1, S3W1h, S3W1l, s3w2, S3W2h, S3W2l,
        s2w0, s2b0, Wc0, W0h, W0l, s2w1, W1h, W1l, s2w2, W2h, W2l);
    bq_kernel<4096, 32, true, 1024><<<1024, 1024, 0, stream>>>(
        (float)(0.2 * 0.2), xyz, l1_xyz, gidx1, 512);
    {
        dim3 g(257, 32);   // x==256 -> fps2 for batch y
        mlp1_kernel<<<g, 256, 0, stream>>>(xyz, l1_xyz, l2_xyz, gidx1,
            Wc1, M1W1h, M1W1l, s1b1, M1W2h, M1W2l, s1b2, l1p);
    }

    // Stage 2
    bq_kernel<512, 64, false, 1024><<<256, 1024, 0, stream>>>(
        (float)(0.4 * 0.4), l1_xyz, l2_xyz, gidx2, 128);
    mlp2_kernel<<<4096, 256, 0, stream>>>(l1_xyz, l1p, l2_xyz, gidx2,
        W0h, W0l, Wc0, W1h, W1l, s2b1, W2h, W2l, s2b2, X3p);

    // Stage 3 (MFMA GEMMs; gemm3 fuses the 128-row max into P3)
    {
        dim3 g1(64, 4);
        gemm_mfma_kernel<9,  false><<<g1, 256, 0, stream>>>(X3p, 288, S3W0h, S3W0l, s3b0, Y1, 256);
        dim3 g2(64, 8);
        gemm_mfma_kernel<8,  false><<<g2, 256, 0, stream>>>(Y1, 256, S3W1h, S3W1l, s3b1, Y2, 512);
        dim3 g3(64, 16);
        gemm_mfma_kernel<16, true ><<<g3, 256, 0, stream>>>(Y2, 512, S3W2h, S3W2l, s3b2, P3, 1024);
    }

    // Fused FC head (row-max of P3 + 1024->512->256->6)
    fchead_kernel<<<32, 256, 0, stream>>>(P3, f1w, f1b, f2w, f2b, f3w, f3b, (float*)d_out);
    (void)in_sizes; (void)n_in; (void)out_size; (void)ws_size;
}

// Round 13
// 783.641 us; speedup vs baseline: 2.0058x; 1.1486x over previous
//
#include <hip/hip_runtime.h>
#include <hip/hip_bf16.h>

// ---------------------------------------------------------------------------
// PointNet++ critic forward. B=32, N=4096.
// R13: single-pass bf16 MFMA (no hi/lo split). Precision budget: threshold
// 2.76e-5 vs ref max ~1.4e-3 => ~8 bf16-ulps; MLP outputs only flow through
// continuous ops (discrete fps/bq use exact coords), so plain bf16 rounding
// (~2-3 ulps composed) fits. 3x fewer MFMAs, 4x less conversion VALU, half
// the weight bytes. FPS kept at R12 form (established near-structural floor).
// ---------------------------------------------------------------------------

typedef __attribute__((ext_vector_type(8))) short short8;
typedef __attribute__((ext_vector_type(4))) float f32x4;
union SV8 { short8 v; ushort u[8]; };

__device__ __forceinline__ ushort f2bf(float x) {
    unsigned u = __float_as_uint(x);
    unsigned r = (u + 0x7fffu + ((u >> 16) & 1u)) >> 16;   // RNE
    return (ushort)r;
}

// ======================= DPP wave64 max-reduce (u64) =======================
template<int CTRL>
__device__ __forceinline__ unsigned long long dpp_mov_u64(unsigned long long x) {
    const int lo = (int)(unsigned)(x & 0xffffffffull);
    const int hi = (int)(unsigned)(x >> 32);
    const int nlo = __builtin_amdgcn_update_dpp(lo, lo, CTRL, 0xf, 0xf, false);
    const int nhi = __builtin_amdgcn_update_dpp(hi, hi, CTRL, 0xf, 0xf, false);
    return ((unsigned long long)(unsigned)nhi << 32) | (unsigned)nlo;
}

__device__ __forceinline__ unsigned long long wave_max_u64(unsigned long long x) {
    unsigned long long y;
    y = dpp_mov_u64<0x111>(x); if (y > x) x = y;   // row_shr:1
    y = dpp_mov_u64<0x112>(x); if (y > x) x = y;   // row_shr:2
    y = dpp_mov_u64<0x114>(x); if (y > x) x = y;   // row_shr:4
    y = dpp_mov_u64<0x118>(x); if (y > x) x = y;   // row_shr:8
    y = dpp_mov_u64<0x142>(x); if (y > x) x = y;   // row_bcast:15
    y = dpp_mov_u64<0x143>(x); if (y > x) x = y;   // row_bcast:31
    return x;
}

// ============================ FPS body (R12) ===============================
template<int N, int S, int NT, bool CHW>
__device__ __forceinline__ void fps_body(const float* __restrict__ xyz,
                                         float* __restrict__ new_xyz,
                                         int b, int t, char* smem) {
    constexpr int P  = N / NT;
    constexpr int NW = NT / 64;
    float4* sxyz = (float4*)smem;
    unsigned long long* rv = (unsigned long long*)(smem + (size_t)N * 16);
    int* sfar = (int*)(smem + (size_t)N * 16 + 2 * NW * 8);
    float px[P], py[P], pz[P], dist[P];
    unsigned idc[P];
    if (CHW) {
        const float* base = xyz + (size_t)b * 3 * N;
        #pragma unroll
        for (int p = 0; p < P; ++p) {
            const int i = p * NT + t;
            px[p] = base[i]; py[p] = base[N + i]; pz[p] = base[2 * N + i];
            sxyz[i] = make_float4(px[p], py[p], pz[p], 0.0f);
        }
    } else {
        const float* base = xyz + (size_t)b * N * 3;
        #pragma unroll
        for (int p = 0; p < P; ++p) {
            const int i = p * NT + t;
            px[p] = base[i*3]; py[p] = base[i*3+1]; pz[p] = base[i*3+2];
            sxyz[i] = make_float4(px[p], py[p], pz[p], 0.0f);
        }
    }
    #pragma unroll
    for (int p = 0; p < P; ++p) { dist[p] = 1e10f; idc[p] = (unsigned)(N - 1 - (p * NT + t)); }
    __syncthreads();
    int far = 0;
    for (int j = 0; j < S; ++j) {
        if (t == 0) sfar[j] = far;           // LDS only — no VMEM in loop
        const float4 cen = sxyz[far];        // broadcast b128
        unsigned long long pk[P];
        #pragma unroll
        for (int p = 0; p < P; ++p) {
            const float dx = px[p] - cen.x, dy = py[p] - cen.y, dz = pz[p] - cen.z;
            // match reference rounding exactly: no FMA contraction
            const float d = __fadd_rn(__fadd_rn(__fmul_rn(dx, dx), __fmul_rn(dy, dy)), __fmul_rn(dz, dz));
            const float nd = fminf(dist[p], d);
            dist[p] = nd;
            pk[p] = ((unsigned long long)__float_as_uint(nd) << 32) | idc[p];
        }
        #pragma unroll
        for (int s = P / 2; s > 0; s >>= 1)
            #pragma unroll
            for (int k = 0; k < s; ++k)
                if (pk[k + s] > pk[k]) pk[k] = pk[k + s];
        unsigned long long best = wave_max_u64(pk[0]);
        if constexpr (NW > 1) {
            const int sl = (j & 1) * NW;     // parity slots: overwrite-safe
            if ((t & 63) == 63) rv[sl + (t >> 6)] = best;
            __syncthreads();
            unsigned long long bb = rv[sl];
            #pragma unroll
            for (int w = 1; w < NW; ++w) { const unsigned long long v = rv[sl + w]; if (v > bb) bb = v; }
            far = N - 1 - (int)(bb & 0xffffffffull);
        } else {
            far = N - 1 - __builtin_amdgcn_readlane((int)(best & 0xffffffffull), 63);
        }
    }
    __syncthreads();
    float* out = new_xyz + (size_t)b * S * 3;
    for (int i = t; i < S; i += NT) {
        const float4 c = sxyz[sfar[i]];
        out[i*3+0] = c.x; out[i*3+1] = c.y; out[i*3+2] = c.z;
    }
}

// ==================== weight bf16 tile pack (h only) =======================
__device__ __forceinline__ void packg(const float* __restrict__ src,
                                      ushort* __restrict__ dh,
                                      int Ktot, int otiles, int cofs, int idx) {
    const int j = idx & 7, lane = (idx >> 3) & 63;
    const int ot = (idx >> 9) % otiles;
    const int ks = idx / (512 * otiles);
    const int m = lane & 15, q = lane >> 4;
    const int o = ot * 16 + m, c = cofs + ks * 32 + q * 8 + j;
    const float v = (c < Ktot) ? src[(size_t)o * Ktot + c] : 0.0f;
    dh[idx] = f2bf(v);
}

// ================= fps1 + weight pack, merged launch =======================
__global__ __launch_bounds__(256)
void fps1_prep_kernel(const float* __restrict__ xyz, float* __restrict__ l1xyz,
                 const float* s1w0, const float* s1b0, float4* Wc1,
                 const float* s1w1, ushort* M1W1h,
                 const float* s1w2, ushort* M1W2h,
                 const float* s3w0, ushort* S3W0h,
                 const float* s3w1, ushort* S3W1h,
                 const float* s3w2, ushort* S3W2h,
                 const float* s2w0, const float* s2b0, float4* Wc0,
                 ushort* W0h,
                 const float* s2w1, ushort* W1h,
                 const float* s2w2, ushort* W2h) {
    __shared__ __align__(16) char smem[4096 * 16 + 64 + 512 * 4];
    if (blockIdx.x < 32) {
        fps_body<4096, 512, 256, true>(xyz, l1xyz, blockIdx.x, threadIdx.x, smem);
        return;
    }
    int i = (blockIdx.x - 32) * 256 + threadIdx.x;
    if (i < 64)     { Wc1[i] = make_float4(s1w0[i*3], s1w0[i*3+1], s1w0[i*3+2], s1b0[i]); return; }  i -= 64;
    if (i < 4096)   { packg(s1w1, M1W1h,  64,  4, 0, i); return; }   i -= 4096;
    if (i < 8192)   { packg(s1w2, M1W2h,  64,  8, 0, i); return; }   i -= 8192;
    if (i < 73728)  { packg(s3w0, S3W0h, 259, 16, 0, i); return; }   i -= 73728;
    if (i < 131072) { packg(s3w1, S3W1h, 256, 32, 0, i); return; }   i -= 131072;
    if (i < 524288) { packg(s3w2, S3W2h, 512, 64, 0, i); return; }   i -= 524288;
    if (i < 16384)  { packg(s2w0, W0h, 131,  8, 3, i); return; }     i -= 16384;
    if (i < 16384)  { packg(s2w1, W1h, 128,  8, 0, i); return; }     i -= 16384;
    if (i < 32768)  { packg(s2w2, W2h, 128, 16, 0, i); return; }     i -= 32768;
    if (i < 128) {
        Wc0[i] = make_float4(s2w0[(size_t)i*131+0], s2w0[(size_t)i*131+1],
                             s2w0[(size_t)i*131+2], s2b0[i]);
    }
}

// ============================ Ball query ===================================
template<int N, int NS, bool CHW, int NT>
__global__ __launch_bounds__(NT)
void bq_kernel(float r2, const float* __restrict__ xyz, const float* __restrict__ cen,
               int* __restrict__ gidx, int S) {
    constexpr int WPB = NT / 64;
    __shared__ __align__(16) float4 sp[N];
    const int t = threadIdx.x, lane = t & 63, w = t >> 6;
    const int cen0 = blockIdx.x * WPB;
    const int b = cen0 / S;                     // WPB divides S -> same batch
    if (CHW) {
        const float* base = xyz + (size_t)b * 3 * N;
        for (int i = t; i < N; i += NT)
            sp[i] = make_float4(base[i], base[N + i], base[2 * N + i], 0.0f);
    } else {
        const float* base = xyz + (size_t)b * N * 3;
        for (int i = t; i < N; i += NT)
            sp[i] = make_float4(base[i*3], base[i*3+1], base[i*3+2], 0.0f);
    }
    __syncthreads();
    const int wid = cen0 + w;
    const float cx = cen[(size_t)wid*3+0], cy = cen[(size_t)wid*3+1], cz = cen[(size_t)wid*3+2];
    int* out = gidx + (size_t)wid * NS;
    int cnt = 0, first = -1;
    for (int b0 = 0; b0 < N; b0 += 64) {
        const float4 p = sp[b0 + lane];
        const float dx = p.x - cx, dy = p.y - cy, dz = p.z - cz;
        const float d = __fadd_rn(__fadd_rn(__fmul_rn(dx, dx), __fmul_rn(dy, dy)), __fmul_rn(dz, dz));
        const bool in = (d <= r2);
        const unsigned long long m = __ballot(in);
        if (first < 0 && m != 0ull) first = b0 + __ffsll((unsigned long long)m) - 1;
        const int pos = cnt + (int)__popcll(m & ((1ull << lane) - 1ull));
        if (in && pos < NS) out[pos] = b0 + lane;
        cnt += (int)__popcll(m);
        if (cnt >= NS) break;
    }
    if (cnt < NS)
        for (int k = cnt + lane; k < NS; k += 64) out[k] = first;
}

// ==================== MLP stage 1 (MFMA bf16) + fps2 merged ================
__global__ __launch_bounds__(256)
void mlp1_kernel(const float* __restrict__ xyz, const float* __restrict__ l1xyz,
                 float* __restrict__ l2xyz,
                 const int* __restrict__ gidx, const float4* __restrict__ Wc1,
                 const ushort* __restrict__ W1h, const float* __restrict__ b1,
                 const ushort* __restrict__ W2h, const float* __restrict__ b2,
                 float* __restrict__ l1p) {
    __shared__ __align__(16) char smem[64 * 68 * 4 * 2];   // 34816 B
    float* bufA = (float*)smem;
    float* bufB = (float*)(smem + 64 * 68 * 4);
    const int t = threadIdx.x, b = blockIdx.y;
    if (blockIdx.x == 256) {   // fps2
        fps_body<512, 128, 256, false>(l1xyz, l2xyz, b, t, smem);
        return;
    }
    const int s0 = blockIdx.x * 2;
    {
        const int n = t >> 2, c = t & 3;
        const int s = s0 + (n >> 5);
        const int gi = gidx[((size_t)b * 512 + s) * 32 + (n & 31)];
        float v = 0.0f;
        if (c < 3) v = xyz[(size_t)b * 3 * 4096 + c * 4096 + gi] - l1xyz[((size_t)b * 512 + s) * 3 + c];
        bufB[n * 4 + c] = v;
    }
    __syncthreads();
    {   // layer0: 3 -> 64, exact fp32
        const int o = t & 63, ng = t >> 6;
        const float4 wc = Wc1[o];
        #pragma unroll
        for (int r = 0; r < 16; ++r) {
            const int n = ng * 16 + r;
            const float z = wc.w + wc.x * bufB[n*4] + wc.y * bufB[n*4+1] + wc.z * bufB[n*4+2];
            bufA[n * 68 + o] = fmaxf(z, 0.0f);
        }
    }
    const int lane = t & 63, wv = t >> 6;
    const int m = lane & 15, q = lane >> 4;
    const int rowA = wv * 16 + m;
    // layer1: 64 -> 64
    f32x4 acc1[4];
    #pragma unroll
    for (int ot = 0; ot < 4; ++ot)
        #pragma unroll
        for (int r = 0; r < 4; ++r) acc1[ot][r] = 0.0f;
    #pragma unroll
    for (int ks = 0; ks < 2; ++ks) {
        float xv[8];
        *(float4*)&xv[0] = *(const float4*)&bufA[rowA * 68 + ks * 32 + q * 8];
        *(float4*)&xv[4] = *(const float4*)&bufA[rowA * 68 + ks * 32 + q * 8 + 4];
        SV8 ah;
        #pragma unroll
        for (int j = 0; j < 8; ++j) ah.u[j] = f2bf(xv[j]);
        #pragma unroll
        for (int ot = 0; ot < 4; ++ot) {
            SV8 bh;
            bh.v = *(const short8*)(W1h + (size_t)((ks * 4 + ot) * 64 + lane) * 8);
            acc1[ot] = __builtin_amdgcn_mfma_f32_16x16x32_bf16(ah.v, bh.v, acc1[ot], 0, 0, 0);
        }
    }
    #pragma unroll
    for (int ot = 0; ot < 4; ++ot) {
        const float bb = b1[ot * 16 + m];
        #pragma unroll
        for (int r = 0; r < 4; ++r)
            bufB[(wv * 16 + q * 4 + r) * 68 + ot * 16 + m] = fmaxf(acc1[ot][r] + bb, 0.0f);
    }
    // layer2: 64 -> 128 + per-wave max
    f32x4 acc2[8];
    #pragma unroll
    for (int ot = 0; ot < 8; ++ot)
        #pragma unroll
        for (int r = 0; r < 4; ++r) acc2[ot][r] = 0.0f;
    #pragma unroll
    for (int ks = 0; ks < 2; ++ks) {
        float xv[8];
        *(float4*)&xv[0] = *(const float4*)&bufB[rowA * 68 + ks * 32 + q * 8];
        *(float4*)&xv[4] = *(const float4*)&bufB[rowA * 68 + ks * 32 + q * 8 + 4];
        SV8 ah;
        #pragma unroll
        for (int j = 0; j < 8; ++j) ah.u[j] = f2bf(xv[j]);
        #pragma unroll
        for (int ot = 0; ot < 8; ++ot) {
            SV8 bh;
            bh.v = *(const short8*)(W2h + (size_t)((ks * 8 + ot) * 64 + lane) * 8);
            acc2[ot] = __builtin_amdgcn_mfma_f32_16x16x32_bf16(ah.v, bh.v, acc2[ot], 0, 0, 0);
        }
    }
    __syncthreads();
    #pragma unroll
    for (int ot = 0; ot < 8; ++ot) {
        const float bb = b2[ot * 16 + m];
        float mx = 0.0f;
        #pragma unroll
        for (int r = 0; r < 4; ++r) mx = fmaxf(mx, acc2[ot][r] + bb);
        bufA[(wv * 4 + q) * 128 + ot * 16 + m] = mx;
    }
    __syncthreads();
    {
        const int half = t >> 7, o = t & 127;
        float v = bufA[(half * 8) * 128 + o];
        #pragma unroll
        for (int rr = 1; rr < 8; ++rr) v = fmaxf(v, bufA[(half * 8 + rr) * 128 + o]);
        l1p[((size_t)b * 512 + s0 + half) * 128 + o] = v;
    }
}

// ============================ MLP stage 2 (MFMA bf16) ======================
__global__ __launch_bounds__(256)
void mlp2_kernel(const float* __restrict__ l1xyz, const float* __restrict__ l1p,
                 const float* __restrict__ l2xyz, const int* __restrict__ gidx,
                 const ushort* __restrict__ W0h, const float4* __restrict__ Wc0,
                 const ushort* __restrict__ W1h, const float* __restrict__ b1,
                 const ushort* __restrict__ W2h, const float* __restrict__ b2,
                 float* __restrict__ X3) {
    __shared__ __align__(16) float Abuf[64 * 132];   // x / h2
    __shared__ __align__(16) float Bbuf[64 * 132];   // h1 / max-partials
    __shared__ int sg[64];
    const int t = threadIdx.x, bs = blockIdx.x, b = bs >> 7;
    if (t < 64) sg[t] = gidx[(size_t)bs * 64 + t];
    if (t < 3)  X3[(size_t)bs * 288 + t] = l2xyz[(size_t)bs * 3 + t];     // raw coords
    if (t >= 64 && t < 93) X3[(size_t)bs * 288 + 259 + (t - 64)] = 0.0f;  // zero pad
    __syncthreads();
    for (int i = t; i < 64 * 32; i += 256) {
        const int n = i >> 5, cc = i & 31;
        *(float4*)&Abuf[n * 132 + cc * 4] =
            *(const float4*)&l1p[((size_t)b * 512 + sg[n]) * 128 + cc * 4];
    }
    if (t < 192) {
        const int n = t / 3, c = t % 3;
        Abuf[n * 132 + 128 + c] =
            l1xyz[((size_t)b * 512 + sg[n]) * 3 + c] - l2xyz[(size_t)bs * 3 + c];
    }
    __syncthreads();
    const int lane = t & 63, wv = t >> 6;
    const int m = lane & 15, q = lane >> 4;
    const int rowA = wv * 16 + m;

    // layer 0: feats (K=128) MFMA + coords/bias epilogue
    f32x4 acc0[8];
    #pragma unroll
    for (int ot = 0; ot < 8; ++ot)
        #pragma unroll
        for (int r = 0; r < 4; ++r) acc0[ot][r] = 0.0f;
    #pragma unroll
    for (int ks = 0; ks < 4; ++ks) {
        float xv[8];
        *(float4*)&xv[0] = *(const float4*)&Abuf[rowA * 132 + ks * 32 + q * 8];
        *(float4*)&xv[4] = *(const float4*)&Abuf[rowA * 132 + ks * 32 + q * 8 + 4];
        SV8 ah;
        #pragma unroll
        for (int j = 0; j < 8; ++j) ah.u[j] = f2bf(xv[j]);
        #pragma unroll
        for (int ot = 0; ot < 8; ++ot) {
            SV8 bh;
            bh.v = *(const short8*)(W0h + (size_t)((ks * 8 + ot) * 64 + lane) * 8);
            acc0[ot] = __builtin_amdgcn_mfma_f32_16x16x32_bf16(ah.v, bh.v, acc0[ot], 0, 0, 0);
        }
    }
    float crd[4][3];
    #pragma unroll
    for (int r = 0; r < 4; ++r) {
        const int n = wv * 16 + q * 4 + r;
        crd[r][0] = Abuf[n * 132 + 128];
        crd[r][1] = Abuf[n * 132 + 129];
        crd[r][2] = Abuf[n * 132 + 130];
    }
    #pragma unroll
    for (int ot = 0; ot < 8; ++ot) {
        const float4 wc = Wc0[ot * 16 + m];
        #pragma unroll
        for (int r = 0; r < 4; ++r) {
            const float v = acc0[ot][r] + wc.w + wc.x * crd[r][0] + wc.y * crd[r][1] + wc.z * crd[r][2];
            Bbuf[(wv * 16 + q * 4 + r) * 132 + ot * 16 + m] = fmaxf(v, 0.0f);
        }
    }
    __syncthreads();

    // layer 1: 128 -> 128
    f32x4 acc1[8];
    #pragma unroll
    for (int ot = 0; ot < 8; ++ot)
        #pragma unroll
        for (int r = 0; r < 4; ++r) acc1[ot][r] = 0.0f;
    #pragma unroll
    for (int ks = 0; ks < 4; ++ks) {
        float xv[8];
        *(float4*)&xv[0] = *(const float4*)&Bbuf[rowA * 132 + ks * 32 + q * 8];
        *(float4*)&xv[4] = *(const float4*)&Bbuf[rowA * 132 + ks * 32 + q * 8 + 4];
        SV8 ah;
        #pragma unroll
        for (int j = 0; j < 8; ++j) ah.u[j] = f2bf(xv[j]);
        #pragma unroll
        for (int ot = 0; ot < 8; ++ot) {
            SV8 bh;
            bh.v = *(const short8*)(W1h + (size_t)((ks * 8 + ot) * 64 + lane) * 8);
            acc1[ot] = __builtin_amdgcn_mfma_f32_16x16x32_bf16(ah.v, bh.v, acc1[ot], 0, 0, 0);
        }
    }
    __syncthreads();
    #pragma unroll
    for (int ot = 0; ot < 8; ++ot) {
        const float bb = b1[ot * 16 + m];
        #pragma unroll
        for (int r = 0; r < 4; ++r)
            Abuf[(wv * 16 + q * 4 + r) * 132 + ot * 16 + m] = fmaxf(acc1[ot][r] + bb, 0.0f);
    }
    __syncthreads();

    // layer 2: 128 -> 256, relu+max
    f32x4 acc2[16];
    #pragma unroll
    for (int ot = 0; ot < 16; ++ot)
        #pragma unroll
        for (int r = 0; r < 4; ++r) acc2[ot][r] = 0.0f;
    #pragma unroll
    for (int ks = 0; ks < 4; ++ks) {
        float xv[8];
        *(float4*)&xv[0] = *(const float4*)&Abuf[rowA * 132 + ks * 32 + q * 8];
        *(float4*)&xv[4] = *(const float4*)&Abuf[rowA * 132 + ks * 32 + q * 8 + 4];
        SV8 ah;
        #pragma unroll
        for (int j = 0; j < 8; ++j) ah.u[j] = f2bf(xv[j]);
        #pragma unroll
        for (int ot = 0; ot < 16; ++ot) {
            SV8 bh;
            bh.v = *(const short8*)(W2h + (size_t)((ks * 16 + ot) * 64 + lane) * 8);
            acc2[ot] = __builtin_amdgcn_mfma_f32_16x16x32_bf16(ah.v, bh.v, acc2[ot], 0, 0, 0);
        }
    }
    __syncthreads();
    #pragma unroll
    for (int ot = 0; ot < 16; ++ot) {
        const float bb = b2[ot * 16 + m];
        float mx = 0.0f;
        #pragma unroll
        for (int r = 0; r < 4; ++r) mx = fmaxf(mx, acc2[ot][r] + bb);
        Bbuf[(wv * 4 + q) * 256 + ot * 16 + m] = mx;
    }
    __syncthreads();
    {
        float v = Bbuf[t];
        #pragma unroll
        for (int rr = 1; rr < 16; ++rr) v = fmaxf(v, Bbuf[rr * 256 + t]);
        X3[(size_t)bs * 288 + 3 + t] = v;
    }
}

// ===================== stage-3 GEMM via MFMA bf16 (no LDS A) ===============
template<int KSTEPS, bool MAXOUT>
__global__ __launch_bounds__(256)
void gemm_mfma_kernel(const float* __restrict__ A, int AS,
                      const ushort* __restrict__ Wh,
                      const float* __restrict__ bias, float* __restrict__ C, int O) {
    __shared__ float part[16][64];
    const int t = threadIdx.x, lane = t & 63, wv = t >> 6;
    const int m = lane & 15, q = lane >> 4;
    const int rowA = blockIdx.x * 64 + wv * 16 + m;
    const int bo = blockIdx.y, OT = O >> 4;
    f32x4 acc[4];
    #pragma unroll
    for (int ot = 0; ot < 4; ++ot)
        #pragma unroll
        for (int r = 0; r < 4; ++r) acc[ot][r] = 0.0f;
    for (int ks = 0; ks < KSTEPS; ++ks) {
        float xv[8];
        *(float4*)&xv[0] = *(const float4*)&A[(size_t)rowA * AS + ks * 32 + q * 8];
        *(float4*)&xv[4] = *(const float4*)&A[(size_t)rowA * AS + ks * 32 + q * 8 + 4];
        SV8 ah;
        #pragma unroll
        for (int j = 0; j < 8; ++j) ah.u[j] = f2bf(xv[j]);
        #pragma unroll
        for (int ot = 0; ot < 4; ++ot) {
            const size_t wb = (size_t)((ks * OT + bo * 4 + ot) * 64 + lane) * 8;
            SV8 bh;
            bh.v = *(const short8*)(Wh + wb);
            acc[ot] = __builtin_amdgcn_mfma_f32_16x16x32_bf16(ah.v, bh.v, acc[ot], 0, 0, 0);
        }
    }
    if (!MAXOUT) {
        #pragma unroll
        for (int ot = 0; ot < 4; ++ot) {
            const int col = (bo * 4 + ot) * 16 + m;
            const float bb = bias[col];
            #pragma unroll
            for (int r = 0; r < 4; ++r) {
                const int row = blockIdx.x * 64 + wv * 16 + q * 4 + r;
                C[(size_t)row * O + col] = fmaxf(acc[ot][r] + bb, 0.0f);
            }
        }
    } else {
        #pragma unroll
        for (int ot = 0; ot < 4; ++ot) {
            const int col = (bo * 4 + ot) * 16 + m;
            const float bb = bias[col];
            float mx = 0.0f;
            #pragma unroll
            for (int r = 0; r < 4; ++r) mx = fmaxf(mx, acc[ot][r] + bb);
            part[wv * 4 + q][ot * 16 + m] = mx;
        }
        __syncthreads();
        if (t < 64) {
            float v = part[0][t];
            #pragma unroll
            for (int rr = 1; rr < 16; ++rr) v = fmaxf(v, part[rr][t]);
            C[(size_t)blockIdx.x * O + bo * 64 + t] = v;
        }
    }
}

// ================= fused FC head (P3 row-max + 3 layers, fp32) =============
__global__ __launch_bounds__(256)
void fchead_kernel(const float* __restrict__ P3,
                   const float* __restrict__ f1w, const float* __restrict__ f1b,
                   const float* __restrict__ f2w, const float* __restrict__ f2b,
                   const float* __restrict__ f3w, const float* __restrict__ f3b,
                   float* __restrict__ out) {
    __shared__ __align__(16) float x[1024];
    __shared__ __align__(16) float h1[512];
    __shared__ __align__(16) float h2[256];
    const int t = threadIdx.x, b = blockIdx.x;
    for (int i = t; i < 1024; i += 256)
        x[i] = fmaxf(P3[(size_t)(2*b)*1024 + i], P3[(size_t)(2*b+1)*1024 + i]);
    __syncthreads();
    #pragma unroll
    for (int oo = 0; oo < 2; ++oo) {       // f1: 1024 -> 512
        const int o = t + oo * 256;
        const float4* wr = (const float4*)(f1w + (size_t)o * 1024);
        float s0 = 0, s1 = 0, s2 = 0, s3 = 0;
        for (int c = 0; c < 256; ++c) {
            const float4 w4 = wr[c];
            const float4 xv = *(const float4*)&x[c * 4];
            s0 += w4.x * xv.x; s1 += w4.y * xv.y; s2 += w4.z * xv.z; s3 += w4.w * xv.w;
        }
        h1[o] = fmaxf(f1b[o] + ((s0 + s1) + (s2 + s3)), 0.0f);
    }
    __syncthreads();
    {                                       // f2: 512 -> 256
        const float4* wr = (const float4*)(f2w + (size_t)t * 512);
        float s0 = 0, s1 = 0, s2 = 0, s3 = 0;
        for (int c = 0; c < 128; ++c) {
            const float4 w4 = wr[c];
            const float4 xv = *(const float4*)&h1[c * 4];
            s0 += w4.x * xv.x; s1 += w4.y * xv.y; s2 += w4.z * xv.z; s3 += w4.w * xv.w;
        }
        h2[t] = fmaxf(f2b[t] + ((s0 + s1) + (s2 + s3)), 0.0f);
    }
    __syncthreads();
    if (t < 6) {                            // f3: 256 -> 6
        const float4* wr = (const float4*)(f3w + (size_t)t * 256);
        float s0 = 0, s1 = 0, s2 = 0, s3 = 0;
        for (int c = 0; c < 64; ++c) {
            const float4 w4 = wr[c];
            const float4 xv = *(const float4*)&h2[c * 4];
            s0 += w4.x * xv.x; s1 += w4.y * xv.y; s2 += w4.z * xv.z; s3 += w4.w * xv.w;
        }
        out[b * 6 + t] = f3b[t] + ((s0 + s1) + (s2 + s3));
    }
}

// ============================ launch =======================================
extern "C" void kernel_launch(void* const* d_in, const int* in_sizes, int n_in,
                              void* d_out, int out_size, void* d_ws, size_t ws_size,
                              hipStream_t stream) {
    const float* xyz  = (const float*)d_in[0];
    const float* s1w0 = (const float*)d_in[1];  const float* s1b0 = (const float*)d_in[2];
    const float* s1w1 = (const float*)d_in[3];  const float* s1b1 = (const float*)d_in[4];
    const float* s1w2 = (const float*)d_in[5];  const float* s1b2 = (const float*)d_in[6];
    const float* s2w0 = (const float*)d_in[7];  const float* s2b0 = (const float*)d_in[8];
    const float* s2w1 = (const float*)d_in[9];  const float* s2b1 = (const float*)d_in[10];
    const float* s2w2 = (const float*)d_in[11]; const float* s2b2 = (const float*)d_in[12];
    const float* s3w0 = (const float*)d_in[13]; const float* s3b0 = (const float*)d_in[14];
    const float* s3w1 = (const float*)d_in[15]; const float* s3b1 = (const float*)d_in[16];
    const float* s3w2 = (const float*)d_in[17]; const float* s3b2 = (const float*)d_in[18];
    const float* f1w  = (const float*)d_in[19]; const float* f1b  = (const float*)d_in[20];
    const float* f2w  = (const float*)d_in[21]; const float* f2b  = (const float*)d_in[22];
    const float* f3w  = (const float*)d_in[23]; const float* f3b  = (const float*)d_in[24];

    char* ws = (char*)d_ws;
    float* l1_xyz = (float*)(ws + 0);              // 32*512*3
    int*   gidx1  = (int*)  (ws + 196608);         // 32*512*32
    float* l1p    = (float*)(ws + 2293760);        // 32*512*128
    float* l2_xyz = (float*)(ws + 10682368);       // 32*128*3
    int*   gidx2  = (int*)  (ws + 10731520);       // 32*128*64
    float* X3p    = (float*)(ws + 11780096);       // 4096*288 (zero-padded)
    const size_t PK = 16498688;                    // pack region (h-only now)
    float4* Wc1   = (float4*)(ws + PK + 0);
    ushort* M1W1h = (ushort*)(ws + PK + 1024);
    ushort* M1W2h = (ushort*)(ws + PK + 17408);
    ushort* W0h   = (ushort*)(ws + PK + 50176);
    ushort* W1h   = (ushort*)(ws + PK + 115712);
    ushort* W2h   = (ushort*)(ws + PK + 181248);
    float4* Wc0   = (float4*)(ws + PK + 312320);
    ushort* S3W0h = (ushort*)(ws + PK + 314368);
    ushort* S3W1h = (ushort*)(ws + PK + 609280);
    ushort* S3W2h = (ushort*)(ws + PK + 1133568);
    float* Y1   = (float*)(ws + 19729408);         // 4096*256
    float* Y2   = (float*)(ws + 23923712);         // 4096*512
    float* P3   = (float*)(ws + 32312320);         // 64*1024 partial maxima

    // Stage 1 (fps1 on blocks 0..31, weight pack on blocks 32..)
    fps1_prep_kernel<<<3186, 256, 0, stream>>>(xyz, l1_xyz,
        s1w0, s1b0, Wc1, s1w1, M1W1h, s1w2, M1W2h,
        s3w0, S3W0h, s3w1, S3W1h, s3w2, S3W2h,
        s2w0, s2b0, Wc0, W0h, s2w1, W1h, s2w2, W2h);
    bq_kernel<4096, 32, true, 1024><<<1024, 1024, 0, stream>>>(
        (float)(0.2 * 0.2), xyz, l1_xyz, gidx1, 512);
    {
        dim3 g(257, 32);   // x==256 -> fps2 for batch y
        mlp1_kernel<<<g, 256, 0, stream>>>(xyz, l1_xyz, l2_xyz, gidx1,
            Wc1, M1W1h, s1b1, M1W2h, s1b2, l1p);
    }

    // Stage 2
    bq_kernel<512, 64, false, 1024><<<256, 1024, 0, stream>>>(
        (float)(0.4 * 0.4), l1_xyz, l2_xyz, gidx2, 128);
    mlp2_kernel<<<4096, 256, 0, stream>>>(l1_xyz, l1p, l2_xyz, gidx2,
        W0h, Wc0, W1h, s2b1, W2h, s2b2, X3p);

    // Stage 3 (MFMA GEMMs; gemm3 fuses the 128-row max into P3)
    {
        dim3 g1(64, 4);
        gemm_mfma_kernel<9,  false><<<g1, 256, 0, stream>>>(X3p, 288, S3W0h, s3b0, Y1, 256);
        dim3 g2(64, 8);
        gemm_mfma_kernel<8,  false><<<g2, 256, 0, stream>>>(Y1, 256, S3W1h, s3b1, Y2, 512);
        dim3 g3(64, 16);
        gemm_mfma_kernel<16, true ><<<g3, 256, 0, stream>>>(Y2, 512, S3W2h, s3b2, P3, 1024);
    }

    // Fused FC head (row-max of P3 + 1024->512->256->6)
    fchead_kernel<<<32, 256, 0, stream>>>(P3, f1w, f1b, f2w, f2b, f3w, f3b, (float*)d_out);
    (void)in_sizes; (void)n_in; (void)out_size; (void)ws_size;
}